// Round 11
// baseline (22177.222 us; speedup 1.0000x reference)
//
#include <hip/hip_runtime.h>
#include <math.h>

typedef unsigned long long u64;
typedef __attribute__((ext_vector_type(8))) short short8v;   // 8 bf16 = 4 VGPR
typedef __attribute__((ext_vector_type(4))) float f32x4;
typedef __attribute__((ext_vector_type(4))) unsigned uint4v;

#define LB 64
#define LT 2048
#define LH 256
#define LOUT 256
#define NWG 256

// ---------- ws layout (bytes) ----------
// cnt ints: [0..2047] flags (8 bg x 32 flags x 16-int line);
//           [2048..2056] per-XCD tickets + reg barrier; [2064] flush barrier
#define WS_CNT    0
#define WS_CNT_SZ (12 * 1024)
#define TICK_OFF  2048
// h: [slot(4)][batch(64)][s(16)][kg(4)] 16B units -> 256 KB per layer
#define WS_H1     (64 * 1024)
#define WS_H2     (WS_H1 + 256 * 1024)
#define WS_BIAS   (WS_H2 + 256 * 1024)
#define WS_WT2    (1024 * 1024)          // 4 MB

#define MFMA(a, b, c) __builtin_amdgcn_mfma_f32_16x16x32_bf16(a, b, c, 0, 0, 0)

__device__ __host__ __forceinline__ short bf16_rne(float f) {
    unsigned u = __builtin_bit_cast(unsigned, f);
    unsigned r = (u + 0x7fffu + ((u >> 16) & 1u)) >> 16;
    return (short)r;
}
__device__ __forceinline__ float bf16_to_f(short s) {
    unsigned u = ((unsigned)(unsigned short)s) << 16;
    return __builtin_bit_cast(float, u);
}
__device__ __forceinline__ float fsigm(float g) {
    return __builtin_amdgcn_rcpf(1.f + __builtin_amdgcn_exp2f(g * -1.44269504f));
}
__device__ __forceinline__ float ftanh(float g) {
    return __builtin_amdgcn_rcpf(1.f + __builtin_amdgcn_exp2f(g * -2.88539008f)) * 2.f - 1.f;
}

// ---- cache-scope ops: LOCAL=1 -> sc0 (XCD-L2 coherent);
//      LOCAL=0 -> sc0 sc1 (IC coherent, cross-XCD; r6-proven) ----
template <int LOCAL>
__device__ __forceinline__ int ld_flag(const int* p) {
    int v; u64 a = (u64)p;
    if (LOCAL) asm volatile("global_load_dword %0, %1, off sc0\n\ts_waitcnt vmcnt(0)"
                            : "=&v"(v) : "v"(a) : "memory");
    else       asm volatile("global_load_dword %0, %1, off sc0 sc1\n\ts_waitcnt vmcnt(0)"
                            : "=&v"(v) : "v"(a) : "memory");
    return v;
}
template <int LOCAL>
__device__ __forceinline__ void st_flag(int* p, int v) {
    u64 a = (u64)p;
    if (LOCAL) asm volatile("global_store_dword %0, %1, off sc0" :: "v"(a), "v"(v) : "memory");
    else       asm volatile("global_store_dword %0, %1, off sc0 sc1" :: "v"(a), "v"(v) : "memory");
}
template <int LOCAL>
__device__ __forceinline__ void st_unit(void* p, uint4v d) {
    u64 a = (u64)p;
    if (LOCAL) asm volatile("global_store_dwordx4 %0, %1, off sc0" :: "v"(a), "v"(d) : "memory");
    else       asm volatile("global_store_dwordx4 %0, %1, off sc0 sc1" :: "v"(a), "v"(d) : "memory");
}
template <int LOCAL>
__device__ __forceinline__ void ld_units(u64 a0, u64 a1, u64 a2, u64 a3,
        uint4v& U0, uint4v& U1, uint4v& U2, uint4v& U3,
        uint4v& U4, uint4v& U5, uint4v& U6, uint4v& U7) {
    if (LOCAL) asm volatile(
        "global_load_dwordx4 %0, %8, off sc0\n\t"
        "global_load_dwordx4 %1, %8, off offset:16 sc0\n\t"
        "global_load_dwordx4 %2, %9, off sc0\n\t"
        "global_load_dwordx4 %3, %9, off offset:16 sc0\n\t"
        "global_load_dwordx4 %4, %10, off sc0\n\t"
        "global_load_dwordx4 %5, %10, off offset:16 sc0\n\t"
        "global_load_dwordx4 %6, %11, off sc0\n\t"
        "global_load_dwordx4 %7, %11, off offset:16 sc0\n\t"
        "s_waitcnt vmcnt(0)"
        : "=&v"(U0), "=&v"(U1), "=&v"(U2), "=&v"(U3),
          "=&v"(U4), "=&v"(U5), "=&v"(U6), "=&v"(U7)
        : "v"(a0), "v"(a1), "v"(a2), "v"(a3) : "memory");
    else asm volatile(
        "global_load_dwordx4 %0, %8, off sc0 sc1\n\t"
        "global_load_dwordx4 %1, %8, off offset:16 sc0 sc1\n\t"
        "global_load_dwordx4 %2, %9, off sc0 sc1\n\t"
        "global_load_dwordx4 %3, %9, off offset:16 sc0 sc1\n\t"
        "global_load_dwordx4 %4, %10, off sc0 sc1\n\t"
        "global_load_dwordx4 %5, %10, off offset:16 sc0 sc1\n\t"
        "global_load_dwordx4 %6, %11, off sc0 sc1\n\t"
        "global_load_dwordx4 %7, %11, off offset:16 sc0 sc1\n\t"
        "s_waitcnt vmcnt(0)"
        : "=&v"(U0), "=&v"(U1), "=&v"(U2), "=&v"(U3),
          "=&v"(U4), "=&v"(U5), "=&v"(U6), "=&v"(U7)
        : "v"(a0), "v"(a1), "v"(a2), "v"(a3) : "memory");
}

// ---------------------------------------------------------------------------
// Prologue: split weights into hi/lo bf16 MFMA A-fragments (layout unchanged).
// ---------------------------------------------------------------------------
__global__ void prep_weights(const float* __restrict__ W_ih,
                             const float* __restrict__ W_hh,
                             const float* __restrict__ b_ih,
                             const float* __restrict__ b_hh,
                             unsigned short* __restrict__ Wt2,
                             float* __restrict__ bias_r) {
    int gid = blockIdx.x * 256 + threadIdx.x;       // 2^20 positions
    if (gid >= (1 << 20)) return;
    int j   = gid & 7;
    int rwi = (gid >> 3) & 15;
    int kgi = (gid >> 7) & 3;
    int ks  = (gid >> 9) & 15;
    int mt  = (gid >> 13) & 3;
    int s   = (gid >> 15) & 15;
    int layer = gid >> 19;
    int k   = ks * 32 + kgi * 8 + j;
    int row = mt * 256 + s * 16 + rwi;              // original gate row
    float w = (k < 256) ? W_ih[((size_t)layer * 1024 + row) * 256 + k]
                        : W_hh[((size_t)layer * 1024 + row) * 256 + (k - 256)];
    short hi = bf16_rne(w);
    float rem = w - bf16_to_f(hi);
    short lo = bf16_rne(rem);
    size_t base = (((size_t)((layer * 16 + s) * 4 + mt) * 16 + ks) * 1024)
                  + (size_t)kgi * 128 + rwi * 8 + j;
    Wt2[base]       = (unsigned short)hi;
    Wt2[base + 512] = (unsigned short)lo;
    if (k == 0) {
        int ridx = s * 64 + mt * 16 + rwi;
        bias_r[layer * 1024 + ridx] = b_ih[layer * 1024 + row] + b_hh[layer * 1024 + row];
    }
}

// ---------------------------------------------------------------------------
// Persistent 2-layer LSTM, MFMA split-bf16, XCD-local sync (r9 structure).
// r11 delta vs r9: producer publishes its flag sc0-ONLY (no IC write-through);
// the poll's first vmcnt(0) no longer waits for a cross-die store ack.
// Poller keeps a rare IC-escape read (1/64) purely as a liveness guard.
// ---------------------------------------------------------------------------
__global__ __launch_bounds__(256, 1)
void lstm_persistent(const float* __restrict__ x,
                     const unsigned short* __restrict__ Wt2,
                     const float* __restrict__ bias_r,
                     char* __restrict__ h1c, char* __restrict__ h2c,
                     int* __restrict__ cnt)
{
    __shared__ __align__(16) f32x4 red[12][64];    // cross-wave partials, 12 KB
    __shared__ int s_mode, s_bg, s_role;

    const int tid   = threadIdx.x;
    const int wave  = tid >> 6;
    const int lane  = tid & 63;

    // ---- registration: discover placement ----
    if (tid == 0) {
        unsigned xcc = (unsigned)__builtin_amdgcn_s_getreg(20 | (3 << 11)) & 7u;
        int* tick = cnt + TICK_OFF;
        int tk = __hip_atomic_fetch_add(tick + xcc, 1, __ATOMIC_RELAXED, __HIP_MEMORY_SCOPE_AGENT);
        __hip_atomic_fetch_add(tick + 8, 1, __ATOMIC_RELEASE, __HIP_MEMORY_SCOPE_AGENT);
        while (__hip_atomic_load(tick + 8, __ATOMIC_ACQUIRE, __HIP_MEMORY_SCOPE_AGENT) < NWG)
            __builtin_amdgcn_s_sleep(8);
        int bal = 1;
        for (int i = 0; i < 8; ++i)
            bal &= (__hip_atomic_load(tick + i, __ATOMIC_RELAXED, __HIP_MEMORY_SCOPE_AGENT) == 32);
        s_mode = bal;
        s_bg   = bal ? (int)xcc : (int)(blockIdx.x & 7);
        s_role = bal ? tk : (int)(((blockIdx.x >> 7) << 4) | ((blockIdx.x & 127) >> 3));
    }
    __syncthreads();

    // ---- purge ALL L2s, then grid barrier (kills stale-dirty-line hazard) ----
    __builtin_amdgcn_fence(__ATOMIC_SEQ_CST, "agent");
    __syncthreads();
    if (tid == 0) {
        int* b2 = cnt + TICK_OFF + 16;
        __hip_atomic_fetch_add(b2, 1, __ATOMIC_RELEASE, __HIP_MEMORY_SCOPE_AGENT);
        while (__hip_atomic_load(b2, __ATOMIC_ACQUIRE, __HIP_MEMORY_SCOPE_AGENT) < NWG)
            __builtin_amdgcn_s_sleep(8);
    }
    __syncthreads();

    const int mode  = s_mode;
    const int bg    = s_bg;
    const int layer = s_role >> 4;
    const int s     = s_role & 15;
    const int b0    = bg * 8;
    const int kg    = lane >> 4;       // k-group within frag
    const int rw    = lane & 15;       // row-within-tile / batch col
    const int rb    = rw & 7;          // duplicated batch for lanes 8..15
    const int batch = b0 + rb;
    int* const fl_base = cnt + bg * 256;         // 32 flags, one 64B line each

    // ---- one-time: A-fragments (weights) into registers ----
    short8v Ahi[4][4], Alo[4][4];      // [mt][k2]
    #pragma unroll
    for (int mt = 0; mt < 4; ++mt)
        #pragma unroll
        for (int k2 = 0; k2 < 4; ++k2) {
            size_t base = (((size_t)((layer * 16 + s) * 4 + mt) * 16 + (wave * 4 + k2)) * 1024)
                          + (size_t)kg * 128 + rw * 8;
            Ahi[mt][k2] = *(const short8v*)((const short*)Wt2 + base);
            Alo[mt][k2] = *(const short8v*)((const short*)Wt2 + base + 512);
        }

    f32x4 biasv[4];
    #pragma unroll
    for (int mt = 0; mt < 4; ++mt)
        biasv[mt] = *(const f32x4*)(bias_r + layer * 1024 + s * 64 + mt * 16 + kg * 4);

    f32x4 creg = {0.f, 0.f, 0.f, 0.f};             // cell state (wave 0, rw<8)

    // ---- initial x prefetch (t=0), layer-0 waves 0/1 only ----
    float4 xr[4][2];
    if (layer == 0 && wave < 2) {
        #pragma unroll
        for (int k2 = 0; k2 < 4; ++k2) {
            const int kbase = (wave * 4 + k2) * 32 + kg * 8;
            const float* xp = x + ((size_t)batch * LT + 0) * LH + kbase;
            xr[k2][0] = *(const float4*)xp;
            xr[k2][1] = *(const float4*)(xp + 4);
        }
    }

    for (int r = 0; r <= LT; ++r) {
        const bool active = (layer == 0) ? (r < LT) : (r >= 1);
        const int t = (layer == 0) ? r : (r - 1);

        // ---- acquire B-fragments ----
        short8v Bhi[4], Blo[4];
        bool useB = false;
        if (active) {
            if (layer == 0 && wave < 2) {
                #pragma unroll
                for (int k2 = 0; k2 < 4; ++k2) {
                    float fv[8] = {xr[k2][0].x, xr[k2][0].y, xr[k2][0].z, xr[k2][0].w,
                                   xr[k2][1].x, xr[k2][1].y, xr[k2][1].z, xr[k2][1].w};
                    short8v bh, bl;
                    #pragma unroll
                    for (int j = 0; j < 8; ++j) {
                        short hb = bf16_rne(fv[j]);
                        bh[j] = hb;
                        bl[j] = bf16_rne(fv[j] - bf16_to_f(hb));
                    }
                    Bhi[k2] = bh; Blo[k2] = bl;
                }
                useB = true;
            } else {
                const char* hbuf; int slot, kofs; bool any;
                if (layer == 0)      { any = (t > 0); hbuf = h1c; slot = (t - 1) & 3; kofs = -256; }
                else if (wave < 2)   { any = true;    hbuf = h1c; slot = t & 3;       kofs = 0;    }
                else                 { any = (t > 0); hbuf = h2c; slot = (t - 1) & 3; kofs = -256; }
                if (any) {
                    const int kb0 = wave * 128 + kg * 8 + kofs;
                    u64 a0, a1, a2, a3;
                    {
                        int kb;
                        kb = kb0;       a0 = (u64)(hbuf + (size_t)((((slot * 64 + batch) * 16) + (kb >> 4)) * 4 + ((kb >> 2) & 3)) * 16);
                        kb = kb0 + 32;  a1 = (u64)(hbuf + (size_t)((((slot * 64 + batch) * 16) + (kb >> 4)) * 4 + ((kb >> 2) & 3)) * 16);
                        kb = kb0 + 64;  a2 = (u64)(hbuf + (size_t)((((slot * 64 + batch) * 16) + (kb >> 4)) * 4 + ((kb >> 2) & 3)) * 16);
                        kb = kb0 + 96;  a3 = (u64)(hbuf + (size_t)((((slot * 64 + batch) * 16) + (kb >> 4)) * 4 + ((kb >> 2) & 3)) * 16);
                    }
                    uint4v U0, U1, U2, U3, U4, U5, U6, U7;
                    if (mode) ld_units<1>(a0, a1, a2, a3, U0, U1, U2, U3, U4, U5, U6, U7);
                    else      ld_units<0>(a0, a1, a2, a3, U0, U1, U2, U3, U4, U5, U6, U7);
                    union { unsigned d[4]; short8v v; } bh, bl;
                    bh.d[0] = U0.x; bh.d[1] = U0.y; bh.d[2] = U1.x; bh.d[3] = U1.y; Bhi[0] = bh.v;
                    bl.d[0] = U0.z; bl.d[1] = U0.w; bl.d[2] = U1.z; bl.d[3] = U1.w; Blo[0] = bl.v;
                    bh.d[0] = U2.x; bh.d[1] = U2.y; bh.d[2] = U3.x; bh.d[3] = U3.y; Bhi[1] = bh.v;
                    bl.d[0] = U2.z; bl.d[1] = U2.w; bl.d[2] = U3.z; bl.d[3] = U3.w; Blo[1] = bl.v;
                    bh.d[0] = U4.x; bh.d[1] = U4.y; bh.d[2] = U5.x; bh.d[3] = U5.y; Bhi[2] = bh.v;
                    bl.d[0] = U4.z; bl.d[1] = U4.w; bl.d[2] = U5.z; bl.d[3] = U5.w; Blo[2] = bl.v;
                    bh.d[0] = U6.x; bh.d[1] = U6.y; bh.d[2] = U7.x; bh.d[3] = U7.y; Bhi[3] = bh.v;
                    bl.d[0] = U6.z; bl.d[1] = U6.w; bl.d[2] = U7.z; bl.d[3] = U7.w; Blo[3] = bl.v;
                    useB = true;
                }
            }
        }

        // ---- MFMA chain ----
        f32x4 acc[4];
        #pragma unroll
        for (int mt = 0; mt < 4; ++mt) acc[mt] = (f32x4){0.f, 0.f, 0.f, 0.f};
        if (useB) {
            #pragma unroll
            for (int k2 = 0; k2 < 4; ++k2)
                #pragma unroll
                for (int mt = 0; mt < 4; ++mt) {
                    acc[mt] = MFMA(Ahi[mt][k2], Bhi[k2], acc[mt]);  // hi*hi
                    acc[mt] = MFMA(Ahi[mt][k2], Blo[k2], acc[mt]);  // hi*lo
                    acc[mt] = MFMA(Alo[mt][k2], Bhi[k2], acc[mt]);  // lo*hi
                }
        }

        // ---- cross-wave k-reduction via LDS ----
        if (active && wave > 0) {
            #pragma unroll
            for (int mt = 0; mt < 4; ++mt) red[(wave - 1) * 4 + mt][lane] = acc[mt];
        }
        __syncthreads();

        if (active && wave == 0) {
            f32x4 gate[4];
            #pragma unroll
            for (int mt = 0; mt < 4; ++mt) {
                f32x4 gs = acc[mt] + biasv[mt];
                #pragma unroll
                for (int w = 0; w < 3; ++w) gs += red[w * 4 + mt][lane];
                gate[mt] = gs;
            }
            float hv[4];
            #pragma unroll
            for (int rr = 0; rr < 4; ++rr) {
                float si = fsigm(gate[0][rr]);
                float sf = fsigm(gate[1][rr]);
                float so = fsigm(gate[3][rr]);
                float gg = ftanh(gate[2][rr]);
                float cn = sf * creg[rr] + si * gg;
                creg[rr] = cn;
                hv[rr] = so * ftanh(cn);
            }
            if (rw < 8) {
                u64 qh = 0, ql = 0;
                #pragma unroll
                for (int rr = 0; rr < 4; ++rr) {
                    unsigned short hb = (unsigned short)bf16_rne(hv[rr]);
                    unsigned short lb = (unsigned short)bf16_rne(hv[rr] - bf16_to_f((short)hb));
                    qh |= ((u64)hb) << (16 * rr);
                    ql |= ((u64)lb) << (16 * rr);
                }
                uint4v dd;
                dd.x = (unsigned)qh; dd.y = (unsigned)(qh >> 32);
                dd.z = (unsigned)ql; dd.w = (unsigned)(ql >> 32);
                char* hbuf = (layer == 0 ? h1c : h2c);
                int unit = (((t & 3) * 64 + (b0 + rw)) * 16 + s) * 4 + kg;
                if (mode) st_unit<1>(hbuf + (size_t)unit * 16, dd);
                else      st_unit<0>(hbuf + (size_t)unit * 16, dd);
            }
        }

        // ---- signal: my round r done (h stores drained first) ----
        if (wave == 0 && r < LT) {
            asm volatile("s_waitcnt vmcnt(0)" ::: "memory");   // h stores at coherence pt
            if (lane == 0) {
                int* fp = fl_base + (layer * 16 + s) * 16;
                if (mode) st_flag<1>(fp, r + 1);    // r11: sc0-only, no IC ack on chain
                else      st_flag<0>(fp, r + 1);
            }
        }

        // ---- x prefetch for next round (hides HBM under the poll) ----
        if (layer == 0 && wave < 2 && t + 1 < LT) {
            #pragma unroll
            for (int k2 = 0; k2 < 4; ++k2) {
                const int kbase = (wave * 4 + k2) * 32 + kg * 8;
                const float* xp = x + ((size_t)batch * LT + (t + 1)) * LH + kbase;
                xr[k2][0] = *(const float4*)xp;
                xr[k2][1] = *(const float4*)(xp + 4);
            }
        }

        // ---- wait for round r+1 preconditions (per-layer predicates) ----
        // L0 entering r+1: L0 flags >= r+1, L1 flags >= r-1 (4-slot anti-dep)
        // L1 entering r+1: all 32 flags >= r+1
        if (r < LT) {
            if (wave == 0) {
                const int mL  = lane >> 4;          // member's layer (lanes 0..31)
                const int tgt = (layer == 0) ? ((mL == 0) ? r + 1 : r - 1) : (r + 1);
                int* fp = fl_base + (lane & 31) * 16;
                int it = 0;
                for (;;) {
                    int v = 0x7fffffff;
                    if (lane < 32) {
                        ++it;
                        if (mode && (it & 63) != 0) v = ld_flag<1>(fp);   // local L2
                        else                        v = ld_flag<0>(fp);   // IC escape / mode0
                    }
                    if (__all(v >= tgt)) break;
                    if (!mode) __builtin_amdgcn_s_sleep(1);
                }
            }
            __syncthreads();
        }
    }
}

// ---------------------------------------------------------------------------
// Epilogue: out = h2(2047) @ W_fc^T + b_fc   (slot 3, 16B-unit layout)
// ---------------------------------------------------------------------------
__global__ __launch_bounds__(256)
void fc_kernel(const char* __restrict__ h2c,
               const float* __restrict__ W_fc,
               const float* __restrict__ b_fc,
               float* __restrict__ out) {
    int b = blockIdx.x;
    int o = threadIdx.x;
    __shared__ float hrow[LH];
    for (int k = threadIdx.x; k < LH; k += 256) {
        int unit = ((3 * 64 + b) * 16 + (k >> 4)) * 4 + ((k >> 2) & 3);
        const u64* up = (const u64*)(h2c + (size_t)unit * 16);
        u64 qh = up[0];
        u64 ql = up[1];
        int sh = (k & 3) * 16;
        hrow[k] = bf16_to_f((short)(qh >> sh)) + bf16_to_f((short)(ql >> sh));
    }
    __syncthreads();
    float acc = b_fc[o];
#pragma unroll 8
    for (int k = 0; k < LH; ++k)
        acc = fmaf(W_fc[o * LH + k], hrow[k], acc);
    out[b * LOUT + o] = acc;
}

extern "C" void kernel_launch(void* const* d_in, const int* in_sizes, int n_in,
                              void* d_out, int out_size, void* d_ws, size_t ws_size,
                              hipStream_t stream) {
    const float* x    = (const float*)d_in[0];
    const float* W_ih = (const float*)d_in[1];
    const float* W_hh = (const float*)d_in[2];
    const float* b_ih = (const float*)d_in[3];
    const float* b_hh = (const float*)d_in[4];
    const float* W_fc = (const float*)d_in[5];
    const float* b_fc = (const float*)d_in[6];
    float* out = (float*)d_out;

    char* ws = (char*)d_ws;
    int*            cnt    = (int*)(ws + WS_CNT);
    char*           h1c    = ws + WS_H1;
    char*           h2c    = ws + WS_H2;
    float*          bias_r = (float*)(ws + WS_BIAS);
    unsigned short* Wt2    = (unsigned short*)(ws + WS_WT2);

    hipMemsetAsync(cnt, 0, WS_CNT_SZ, stream);   // fresh flags + tickets each call
    prep_weights<<<(1 << 20) / 256, 256, 0, stream>>>(W_ih, W_hh, b_ih, b_hh, Wt2, bias_r);

    void* args[] = {(void*)&x, (void*)&Wt2, (void*)&bias_r,
                    (void*)&h1c, (void*)&h2c, (void*)&cnt};
    hipError_t e = hipLaunchCooperativeKernel(lstm_persistent, dim3(NWG), dim3(256),
                                              args, 0, stream);
    if (e != hipSuccess) {
        // GPU otherwise idle, 1 WG/CU: 256 WGs co-reside anyway
        lstm_persistent<<<NWG, 256, 0, stream>>>(x, Wt2, bias_r, h1c, h2c, cnt);
    }

    fc_kernel<<<LB, 256, 0, stream>>>(h2c, W_fc, b_fc, out);
}

// Round 13
// 8547.878 us; speedup vs baseline: 2.5945x; 2.5945x over previous
//
#include <hip/hip_runtime.h>
#include <math.h>

typedef unsigned long long u64;
typedef __attribute__((ext_vector_type(8))) short short8v;   // 8 bf16 = 4 VGPR
typedef __attribute__((ext_vector_type(4))) float f32x4;
typedef __attribute__((ext_vector_type(4))) unsigned uint4v;

#define LB 64
#define LT 2048
#define LH 256
#define LOUT 256
#define NWG 256

// ---------- ws layout (bytes) ----------
// cnt ints: [0..2047] flags (8 bg x 32 flags x 16-int line);
//           [2048..2056] per-XCD tickets + reg barrier; [2064] flush barrier
#define WS_CNT    0
#define WS_CNT_SZ (12 * 1024)
#define TICK_OFF  2048
// h: [slot(4)][batch(64)][s(16)][kg(4)] 16B units -> 256 KB per layer
#define WS_H1     (64 * 1024)
#define WS_H2     (WS_H1 + 256 * 1024)
#define WS_BIAS   (WS_H2 + 256 * 1024)
#define WS_WT2    (1024 * 1024)          // 4 MB

#define MFMA(a, b, c) __builtin_amdgcn_mfma_f32_16x16x32_bf16(a, b, c, 0, 0, 0)

__device__ __host__ __forceinline__ short bf16_rne(float f) {
    unsigned u = __builtin_bit_cast(unsigned, f);
    unsigned r = (u + 0x7fffu + ((u >> 16) & 1u)) >> 16;
    return (short)r;
}
__device__ __forceinline__ float bf16_to_f(short s) {
    unsigned u = ((unsigned)(unsigned short)s) << 16;
    return __builtin_bit_cast(float, u);
}
__device__ __forceinline__ float fsigm(float g) {
    return __builtin_amdgcn_rcpf(1.f + __builtin_amdgcn_exp2f(g * -1.44269504f));
}
__device__ __forceinline__ float ftanh(float g) {
    return __builtin_amdgcn_rcpf(1.f + __builtin_amdgcn_exp2f(g * -2.88539008f)) * 2.f - 1.f;
}

// ---- cache-scope ops: LOCAL=1 -> sc0 (XCD-L2 coherent);
//      LOCAL=0 -> sc0 sc1 (IC coherent, cross-XCD; r6-proven) ----
// r9-PROVEN protocol: mode-1 flags are DUAL-PUBLISHED (sc0 then sc0 sc1) and
// polls take an IC-scope read every 8th retry. r11/r12 (sc0-only) hang/regress.
template <int LOCAL>
__device__ __forceinline__ int ld_flag(const int* p) {
    int v; u64 a = (u64)p;
    if (LOCAL) asm volatile("global_load_dword %0, %1, off sc0\n\ts_waitcnt vmcnt(0)"
                            : "=&v"(v) : "v"(a) : "memory");
    else       asm volatile("global_load_dword %0, %1, off sc0 sc1\n\ts_waitcnt vmcnt(0)"
                            : "=&v"(v) : "v"(a) : "memory");
    return v;
}
template <int LOCAL>
__device__ __forceinline__ void st_flag(int* p, int v) {
    u64 a = (u64)p;
    if (LOCAL) asm volatile("global_store_dword %0, %1, off sc0" :: "v"(a), "v"(v) : "memory");
    else       asm volatile("global_store_dword %0, %1, off sc0 sc1" :: "v"(a), "v"(v) : "memory");
}
template <int LOCAL>
__device__ __forceinline__ void st_unit(void* p, uint4v d) {
    u64 a = (u64)p;
    if (LOCAL) asm volatile("global_store_dwordx4 %0, %1, off sc0" :: "v"(a), "v"(d) : "memory");
    else       asm volatile("global_store_dwordx4 %0, %1, off sc0 sc1" :: "v"(a), "v"(d) : "memory");
}
template <int LOCAL>
__device__ __forceinline__ void ld_units(u64 a0, u64 a1, u64 a2, u64 a3,
        uint4v& U0, uint4v& U1, uint4v& U2, uint4v& U3,
        uint4v& U4, uint4v& U5, uint4v& U6, uint4v& U7) {
    if (LOCAL) asm volatile(
        "global_load_dwordx4 %0, %8, off sc0\n\t"
        "global_load_dwordx4 %1, %8, off offset:16 sc0\n\t"
        "global_load_dwordx4 %2, %9, off sc0\n\t"
        "global_load_dwordx4 %3, %9, off offset:16 sc0\n\t"
        "global_load_dwordx4 %4, %10, off sc0\n\t"
        "global_load_dwordx4 %5, %10, off offset:16 sc0\n\t"
        "global_load_dwordx4 %6, %11, off sc0\n\t"
        "global_load_dwordx4 %7, %11, off offset:16 sc0\n\t"
        "s_waitcnt vmcnt(0)"
        : "=&v"(U0), "=&v"(U1), "=&v"(U2), "=&v"(U3),
          "=&v"(U4), "=&v"(U5), "=&v"(U6), "=&v"(U7)
        : "v"(a0), "v"(a1), "v"(a2), "v"(a3) : "memory");
    else asm volatile(
        "global_load_dwordx4 %0, %8, off sc0 sc1\n\t"
        "global_load_dwordx4 %1, %8, off offset:16 sc0 sc1\n\t"
        "global_load_dwordx4 %2, %9, off sc0 sc1\n\t"
        "global_load_dwordx4 %3, %9, off offset:16 sc0 sc1\n\t"
        "global_load_dwordx4 %4, %10, off sc0 sc1\n\t"
        "global_load_dwordx4 %5, %10, off offset:16 sc0 sc1\n\t"
        "global_load_dwordx4 %6, %11, off sc0 sc1\n\t"
        "global_load_dwordx4 %7, %11, off offset:16 sc0 sc1\n\t"
        "s_waitcnt vmcnt(0)"
        : "=&v"(U0), "=&v"(U1), "=&v"(U2), "=&v"(U3),
          "=&v"(U4), "=&v"(U5), "=&v"(U6), "=&v"(U7)
        : "v"(a0), "v"(a1), "v"(a2), "v"(a3) : "memory");
}

// ---------------------------------------------------------------------------
// Prologue: split weights into hi/lo bf16 MFMA A-fragments (layout unchanged).
// ---------------------------------------------------------------------------
__global__ void prep_weights(const float* __restrict__ W_ih,
                             const float* __restrict__ W_hh,
                             const float* __restrict__ b_ih,
                             const float* __restrict__ b_hh,
                             unsigned short* __restrict__ Wt2,
                             float* __restrict__ bias_r) {
    int gid = blockIdx.x * 256 + threadIdx.x;       // 2^20 positions
    if (gid >= (1 << 20)) return;
    int j   = gid & 7;
    int rwi = (gid >> 3) & 15;
    int kgi = (gid >> 7) & 3;
    int ks  = (gid >> 9) & 15;
    int mt  = (gid >> 13) & 3;
    int s   = (gid >> 15) & 15;
    int layer = gid >> 19;
    int k   = ks * 32 + kgi * 8 + j;
    int row = mt * 256 + s * 16 + rwi;              // original gate row
    float w = (k < 256) ? W_ih[((size_t)layer * 1024 + row) * 256 + k]
                        : W_hh[((size_t)layer * 1024 + row) * 256 + (k - 256)];
    short hi = bf16_rne(w);
    float rem = w - bf16_to_f(hi);
    short lo = bf16_rne(rem);
    size_t base = (((size_t)((layer * 16 + s) * 4 + mt) * 16 + ks) * 1024)
                  + (size_t)kgi * 128 + rwi * 8 + j;
    Wt2[base]       = (unsigned short)hi;
    Wt2[base + 512] = (unsigned short)lo;
    if (k == 0) {
        int ridx = s * 64 + mt * 16 + rwi;
        bias_r[layer * 1024 + ridx] = b_ih[layer * 1024 + row] + b_hh[layer * 1024 + row];
    }
}

// ---------------------------------------------------------------------------
// Persistent 2-layer LSTM, MFMA split-bf16, XCD-local sync — EXACT r9
// protocol (dual-publish flags, 1/8 IC-escape polls, purge + grid barrier).
// r13 delta: wave k-range swap (we = wave^2). Waves 2/3 own the x-part
// (k<256: prefetch + convert); waves 0/1 own the h-part. Wave 0 (the poller)
// never issues HBM x loads, so its poll vmcnt(0) no longer eats ~900cy of
// x-prefetch latency each round; waves 2/3's x loads drain under the poll.
// ---------------------------------------------------------------------------
__global__ __launch_bounds__(256, 1)
void lstm_persistent(const float* __restrict__ x,
                     const unsigned short* __restrict__ Wt2,
                     const float* __restrict__ bias_r,
                     char* __restrict__ h1c, char* __restrict__ h2c,
                     int* __restrict__ cnt)
{
    __shared__ __align__(16) f32x4 red[12][64];    // cross-wave partials, 12 KB
    __shared__ int s_mode, s_bg, s_role;

    const int tid   = threadIdx.x;
    const int wave  = tid >> 6;
    const int we    = wave ^ 2;        // k-range owner index (swap 0<->2, 1<->3)
    const int lane  = tid & 63;

    // ---- registration: discover placement ----
    if (tid == 0) {
        unsigned xcc = (unsigned)__builtin_amdgcn_s_getreg(20 | (3 << 11)) & 7u;
        int* tick = cnt + TICK_OFF;
        int tk = __hip_atomic_fetch_add(tick + xcc, 1, __ATOMIC_RELAXED, __HIP_MEMORY_SCOPE_AGENT);
        __hip_atomic_fetch_add(tick + 8, 1, __ATOMIC_RELEASE, __HIP_MEMORY_SCOPE_AGENT);
        while (__hip_atomic_load(tick + 8, __ATOMIC_ACQUIRE, __HIP_MEMORY_SCOPE_AGENT) < NWG)
            __builtin_amdgcn_s_sleep(8);
        int bal = 1;
        for (int i = 0; i < 8; ++i)
            bal &= (__hip_atomic_load(tick + i, __ATOMIC_RELAXED, __HIP_MEMORY_SCOPE_AGENT) == 32);
        s_mode = bal;
        s_bg   = bal ? (int)xcc : (int)(blockIdx.x & 7);
        s_role = bal ? tk : (int)(((blockIdx.x >> 7) << 4) | ((blockIdx.x & 127) >> 3));
    }
    __syncthreads();

    // ---- purge ALL L2s, then grid barrier (kills stale-dirty-line hazard) ----
    __builtin_amdgcn_fence(__ATOMIC_SEQ_CST, "agent");
    __syncthreads();
    if (tid == 0) {
        int* b2 = cnt + TICK_OFF + 16;
        __hip_atomic_fetch_add(b2, 1, __ATOMIC_RELEASE, __HIP_MEMORY_SCOPE_AGENT);
        while (__hip_atomic_load(b2, __ATOMIC_ACQUIRE, __HIP_MEMORY_SCOPE_AGENT) < NWG)
            __builtin_amdgcn_s_sleep(8);
    }
    __syncthreads();

    const int mode  = s_mode;
    const int bg    = s_bg;
    const int layer = s_role >> 4;
    const int s     = s_role & 15;
    const int b0    = bg * 8;
    const int kg    = lane >> 4;       // k-group within frag
    const int rw    = lane & 15;       // row-within-tile / batch col
    const int rb    = rw & 7;          // duplicated batch for lanes 8..15
    const int batch = b0 + rb;
    int* const fl_base = cnt + bg * 256;         // 32 flags, one 64B line each

    // ---- one-time: A-fragments (weights) into registers, k-range = we ----
    short8v Ahi[4][4], Alo[4][4];      // [mt][k2]
    #pragma unroll
    for (int mt = 0; mt < 4; ++mt)
        #pragma unroll
        for (int k2 = 0; k2 < 4; ++k2) {
            size_t base = (((size_t)((layer * 16 + s) * 4 + mt) * 16 + (we * 4 + k2)) * 1024)
                          + (size_t)kg * 128 + rw * 8;
            Ahi[mt][k2] = *(const short8v*)((const short*)Wt2 + base);
            Alo[mt][k2] = *(const short8v*)((const short*)Wt2 + base + 512);
        }

    f32x4 biasv[4];
    #pragma unroll
    for (int mt = 0; mt < 4; ++mt)
        biasv[mt] = *(const f32x4*)(bias_r + layer * 1024 + s * 64 + mt * 16 + kg * 4);

    f32x4 creg = {0.f, 0.f, 0.f, 0.f};             // cell state (wave 0, rw<8)

    // ---- initial x prefetch (t=0): x-part waves (we<2, i.e. waves 2/3) ----
    float4 xr[4][2];
    if (layer == 0 && we < 2) {
        #pragma unroll
        for (int k2 = 0; k2 < 4; ++k2) {
            const int kbase = (we * 4 + k2) * 32 + kg * 8;
            const float* xp = x + ((size_t)batch * LT + 0) * LH + kbase;
            xr[k2][0] = *(const float4*)xp;
            xr[k2][1] = *(const float4*)(xp + 4);
        }
    }

    for (int r = 0; r <= LT; ++r) {
        const bool active = (layer == 0) ? (r < LT) : (r >= 1);
        const int t = (layer == 0) ? r : (r - 1);

        // ---- acquire B-fragments ----
        short8v Bhi[4], Blo[4];
        bool useB = false;
        if (active) {
            if (layer == 0 && we < 2) {
                // x-part (waves 2/3): convert prefetched registers
                #pragma unroll
                for (int k2 = 0; k2 < 4; ++k2) {
                    float fv[8] = {xr[k2][0].x, xr[k2][0].y, xr[k2][0].z, xr[k2][0].w,
                                   xr[k2][1].x, xr[k2][1].y, xr[k2][1].z, xr[k2][1].w};
                    short8v bh, bl;
                    #pragma unroll
                    for (int j = 0; j < 8; ++j) {
                        short hb = bf16_rne(fv[j]);
                        bh[j] = hb;
                        bl[j] = bf16_rne(fv[j] - bf16_to_f(hb));
                    }
                    Bhi[k2] = bh; Blo[k2] = bl;
                }
                useB = true;
            } else {
                const char* hbuf; int slot, kofs; bool any;
                if (layer == 0)      { any = (t > 0); hbuf = h1c; slot = (t - 1) & 3; kofs = -256; }
                else if (we < 2)     { any = true;    hbuf = h1c; slot = t & 3;       kofs = 0;    }
                else                 { any = (t > 0); hbuf = h2c; slot = (t - 1) & 3; kofs = -256; }
                if (any) {
                    const int kb0 = we * 128 + kg * 8 + kofs;
                    u64 a0, a1, a2, a3;
                    {
                        int kb;
                        kb = kb0;       a0 = (u64)(hbuf + (size_t)((((slot * 64 + batch) * 16) + (kb >> 4)) * 4 + ((kb >> 2) & 3)) * 16);
                        kb = kb0 + 32;  a1 = (u64)(hbuf + (size_t)((((slot * 64 + batch) * 16) + (kb >> 4)) * 4 + ((kb >> 2) & 3)) * 16);
                        kb = kb0 + 64;  a2 = (u64)(hbuf + (size_t)((((slot * 64 + batch) * 16) + (kb >> 4)) * 4 + ((kb >> 2) & 3)) * 16);
                        kb = kb0 + 96;  a3 = (u64)(hbuf + (size_t)((((slot * 64 + batch) * 16) + (kb >> 4)) * 4 + ((kb >> 2) & 3)) * 16);
                    }
                    uint4v U0, U1, U2, U3, U4, U5, U6, U7;
                    if (mode) ld_units<1>(a0, a1, a2, a3, U0, U1, U2, U3, U4, U5, U6, U7);
                    else      ld_units<0>(a0, a1, a2, a3, U0, U1, U2, U3, U4, U5, U6, U7);
                    union { unsigned d[4]; short8v v; } bh, bl;
                    bh.d[0] = U0.x; bh.d[1] = U0.y; bh.d[2] = U1.x; bh.d[3] = U1.y; Bhi[0] = bh.v;
                    bl.d[0] = U0.z; bl.d[1] = U0.w; bl.d[2] = U1.z; bl.d[3] = U1.w; Blo[0] = bl.v;
                    bh.d[0] = U2.x; bh.d[1] = U2.y; bh.d[2] = U3.x; bh.d[3] = U3.y; Bhi[1] = bh.v;
                    bl.d[0] = U2.z; bl.d[1] = U2.w; bl.d[2] = U3.z; bl.d[3] = U3.w; Blo[1] = bl.v;
                    bh.d[0] = U4.x; bh.d[1] = U4.y; bh.d[2] = U5.x; bh.d[3] = U5.y; Bhi[2] = bh.v;
                    bl.d[0] = U4.z; bl.d[1] = U4.w; bl.d[2] = U5.z; bl.d[3] = U5.w; Blo[2] = bl.v;
                    bh.d[0] = U6.x; bh.d[1] = U6.y; bh.d[2] = U7.x; bh.d[3] = U7.y; Bhi[3] = bh.v;
                    bl.d[0] = U6.z; bl.d[1] = U6.w; bl.d[2] = U7.z; bl.d[3] = U7.w; Blo[3] = bl.v;
                    useB = true;
                }
            }
        }

        // ---- MFMA chain ----
        f32x4 acc[4];
        #pragma unroll
        for (int mt = 0; mt < 4; ++mt) acc[mt] = (f32x4){0.f, 0.f, 0.f, 0.f};
        if (useB) {
            #pragma unroll
            for (int k2 = 0; k2 < 4; ++k2)
                #pragma unroll
                for (int mt = 0; mt < 4; ++mt) {
                    acc[mt] = MFMA(Ahi[mt][k2], Bhi[k2], acc[mt]);  // hi*hi
                    acc[mt] = MFMA(Ahi[mt][k2], Blo[k2], acc[mt]);  // hi*lo
                    acc[mt] = MFMA(Alo[mt][k2], Bhi[k2], acc[mt]);  // lo*hi
                }
        }

        // ---- cross-wave k-reduction via LDS ----
        if (active && wave > 0) {
            #pragma unroll
            for (int mt = 0; mt < 4; ++mt) red[(wave - 1) * 4 + mt][lane] = acc[mt];
        }
        __syncthreads();

        if (active && wave == 0) {
            f32x4 gate[4];
            #pragma unroll
            for (int mt = 0; mt < 4; ++mt) {
                f32x4 gs = acc[mt] + biasv[mt];
                #pragma unroll
                for (int w = 0; w < 3; ++w) gs += red[w * 4 + mt][lane];
                gate[mt] = gs;
            }
            float hv[4];
            #pragma unroll
            for (int rr = 0; rr < 4; ++rr) {
                float si = fsigm(gate[0][rr]);
                float sf = fsigm(gate[1][rr]);
                float so = fsigm(gate[3][rr]);
                float gg = ftanh(gate[2][rr]);
                float cn = sf * creg[rr] + si * gg;
                creg[rr] = cn;
                hv[rr] = so * ftanh(cn);
            }
            if (rw < 8) {
                u64 qh = 0, ql = 0;
                #pragma unroll
                for (int rr = 0; rr < 4; ++rr) {
                    unsigned short hb = (unsigned short)bf16_rne(hv[rr]);
                    unsigned short lb = (unsigned short)bf16_rne(hv[rr] - bf16_to_f((short)hb));
                    qh |= ((u64)hb) << (16 * rr);
                    ql |= ((u64)lb) << (16 * rr);
                }
                uint4v dd;
                dd.x = (unsigned)qh; dd.y = (unsigned)(qh >> 32);
                dd.z = (unsigned)ql; dd.w = (unsigned)(ql >> 32);
                char* hbuf = (layer == 0 ? h1c : h2c);
                int unit = (((t & 3) * 64 + (b0 + rw)) * 16 + s) * 4 + kg;
                if (mode) st_unit<1>(hbuf + (size_t)unit * 16, dd);
                else      st_unit<0>(hbuf + (size_t)unit * 16, dd);
            }
        }

        // ---- signal: my round r done (h stores drained first) ----
        if (wave == 0 && r < LT) {
            asm volatile("s_waitcnt vmcnt(0)" ::: "memory");   // h stores at coherence pt
            if (lane == 0) {
                int* fp = fl_base + (layer * 16 + s) * 16;
                if (mode) { st_flag<1>(fp, r + 1); st_flag<0>(fp, r + 1); }
                else      st_flag<0>(fp, r + 1);
            }
        }

        // ---- x prefetch for next round: waves 2/3 (we<2); drains under poll ----
        if (layer == 0 && we < 2 && t + 1 < LT) {
            #pragma unroll
            for (int k2 = 0; k2 < 4; ++k2) {
                const int kbase = (we * 4 + k2) * 32 + kg * 8;
                const float* xp = x + ((size_t)batch * LT + (t + 1)) * LH + kbase;
                xr[k2][0] = *(const float4*)xp;
                xr[k2][1] = *(const float4*)(xp + 4);
            }
        }

        // ---- wait for round r+1 preconditions (per-layer predicates) ----
        // L0 entering r+1: L0 flags >= r+1, L1 flags >= r-1 (4-slot anti-dep)
        // L1 entering r+1: all 32 flags >= r+1
        if (r < LT) {
            if (wave == 0) {
                const int mL  = lane >> 4;          // member's layer (lanes 0..31)
                const int tgt = (layer == 0) ? ((mL == 0) ? r + 1 : r - 1) : (r + 1);
                int* fp = fl_base + (lane & 31) * 16;
                int it = 0;
                for (;;) {
                    int v = 0x7fffffff;
                    if (lane < 32) {
                        ++it;
                        if (mode && (it & 7) != 0) v = ld_flag<1>(fp);   // local L2
                        else                       v = ld_flag<0>(fp);   // IC escape / mode0
                    }
                    if (__all(v >= tgt)) break;
                    if (!mode) __builtin_amdgcn_s_sleep(1);
                }
            }
            __syncthreads();
        }
    }
}

// ---------------------------------------------------------------------------
// Epilogue: out = h2(2047) @ W_fc^T + b_fc   (slot 3, 16B-unit layout)
// ---------------------------------------------------------------------------
__global__ __launch_bounds__(256)
void fc_kernel(const char* __restrict__ h2c,
               const float* __restrict__ W_fc,
               const float* __restrict__ b_fc,
               float* __restrict__ out) {
    int b = blockIdx.x;
    int o = threadIdx.x;
    __shared__ float hrow[LH];
    for (int k = threadIdx.x; k < LH; k += 256) {
        int unit = ((3 * 64 + b) * 16 + (k >> 4)) * 4 + ((k >> 2) & 3);
        const u64* up = (const u64*)(h2c + (size_t)unit * 16);
        u64 qh = up[0];
        u64 ql = up[1];
        int sh = (k & 3) * 16;
        hrow[k] = bf16_to_f((short)(qh >> sh)) + bf16_to_f((short)(ql >> sh));
    }
    __syncthreads();
    float acc = b_fc[o];
#pragma unroll 8
    for (int k = 0; k < LH; ++k)
        acc = fmaf(W_fc[o * LH + k], hrow[k], acc);
    out[b * LOUT + o] = acc;
}

extern "C" void kernel_launch(void* const* d_in, const int* in_sizes, int n_in,
                              void* d_out, int out_size, void* d_ws, size_t ws_size,
                              hipStream_t stream) {
    const float* x    = (const float*)d_in[0];
    const float* W_ih = (const float*)d_in[1];
    const float* W_hh = (const float*)d_in[2];
    const float* b_ih = (const float*)d_in[3];
    const float* b_hh = (const float*)d_in[4];
    const float* W_fc = (const float*)d_in[5];
    const float* b_fc = (const float*)d_in[6];
    float* out = (float*)d_out;

    char* ws = (char*)d_ws;
    int*            cnt    = (int*)(ws + WS_CNT);
    char*           h1c    = ws + WS_H1;
    char*           h2c    = ws + WS_H2;
    float*          bias_r = (float*)(ws + WS_BIAS);
    unsigned short* Wt2    = (unsigned short*)(ws + WS_WT2);

    hipMemsetAsync(cnt, 0, WS_CNT_SZ, stream);   // fresh flags + tickets each call
    prep_weights<<<(1 << 20) / 256, 256, 0, stream>>>(W_ih, W_hh, b_ih, b_hh, Wt2, bias_r);

    void* args[] = {(void*)&x, (void*)&Wt2, (void*)&bias_r,
                    (void*)&h1c, (void*)&h2c, (void*)&cnt};
    hipError_t e = hipLaunchCooperativeKernel(lstm_persistent, dim3(NWG), dim3(256),
                                              args, 0, stream);
    if (e != hipSuccess) {
        // GPU otherwise idle, 1 WG/CU: 256 WGs co-reside anyway
        lstm_persistent<<<NWG, 256, 0, stream>>>(x, Wt2, bias_r, h1c, h2c, cnt);
    }

    fc_kernel<<<LB, 256, 0, stream>>>(h2c, W_fc, b_fc, out);
}

// Round 15
// 8398.563 us; speedup vs baseline: 2.6406x; 1.0178x over previous
//
#include <hip/hip_runtime.h>
#include <math.h>

typedef unsigned long long u64;
typedef __attribute__((ext_vector_type(8))) short short8v;   // 8 bf16 = 4 VGPR
typedef __attribute__((ext_vector_type(4))) float f32x4;
typedef __attribute__((ext_vector_type(4))) unsigned uint4v;

#define LB 64
#define LT 2048
#define LH 256
#define LOUT 256
#define NWG 256

// ---------- ws layout (bytes) ----------
// cnt ints: [0..2047] flags (8 bg x 32 flags x 16-int line);
//           [2048..2056] per-XCD tickets + reg barrier; [2064] flush barrier
#define WS_CNT    0
#define WS_CNT_SZ (12 * 1024)
#define TICK_OFF  2048
// h: [slot(8)][batch(64)][s(16)][kg(4)] 16B units -> 512 KB per layer
#define WS_H1     (64 * 1024)
#define WS_H2     (WS_H1 + 512 * 1024)
#define WS_BIAS   (WS_H2 + 512 * 1024)
#define WS_WT2    (2 * 1024 * 1024)      // 4 MB at 2MB..6MB
#define MFMA(a, b, c) __builtin_amdgcn_mfma_f32_16x16x32_bf16(a, b, c, 0, 0, 0)

__device__ __host__ __forceinline__ short bf16_rne(float f) {
    unsigned u = __builtin_bit_cast(unsigned, f);
    unsigned r = (u + 0x7fffu + ((u >> 16) & 1u)) >> 16;
    return (short)r;
}
__device__ __forceinline__ float bf16_to_f(short s) {
    unsigned u = ((unsigned)(unsigned short)s) << 16;
    return __builtin_bit_cast(float, u);
}
__device__ __forceinline__ float fsigm(float g) {
    return __builtin_amdgcn_rcpf(1.f + __builtin_amdgcn_exp2f(g * -1.44269504f));
}
__device__ __forceinline__ float ftanh(float g) {
    return __builtin_amdgcn_rcpf(1.f + __builtin_amdgcn_exp2f(g * -2.88539008f)) * 2.f - 1.f;
}

// ---- cache-scope ops: LOCAL=1 -> sc0 (XCD-L2 coherent);
//      LOCAL=0 -> sc0 sc1 (IC coherent, cross-XCD; r6-proven) ----
// r9-PROVEN protocol: mode-1 flags are DUAL-PUBLISHED (sc0 then sc0 sc1) and
// polls take an IC-scope read every 8th retry. Waitcnt stays INSIDE each asm
// block with its loads (r14 lesson: separate waitcnt asm gets reordered).
template <int LOCAL>
__device__ __forceinline__ int ld_flag(const int* p) {
    int v; u64 a = (u64)p;
    if (LOCAL) asm volatile("global_load_dword %0, %1, off sc0\n\ts_waitcnt vmcnt(0)"
                            : "=&v"(v) : "v"(a) : "memory");
    else       asm volatile("global_load_dword %0, %1, off sc0 sc1\n\ts_waitcnt vmcnt(0)"
                            : "=&v"(v) : "v"(a) : "memory");
    return v;
}
template <int LOCAL>
__device__ __forceinline__ void st_flag(int* p, int v) {
    u64 a = (u64)p;
    if (LOCAL) asm volatile("global_store_dword %0, %1, off sc0" :: "v"(a), "v"(v) : "memory");
    else       asm volatile("global_store_dword %0, %1, off sc0 sc1" :: "v"(a), "v"(v) : "memory");
}
template <int LOCAL>
__device__ __forceinline__ void st_unit(void* p, uint4v d) {
    u64 a = (u64)p;
    if (LOCAL) asm volatile("global_store_dwordx4 %0, %1, off sc0" :: "v"(a), "v"(d) : "memory");
    else       asm volatile("global_store_dwordx4 %0, %1, off sc0 sc1" :: "v"(a), "v"(d) : "memory");
}
template <int LOCAL>
__device__ __forceinline__ void ld_units(u64 a0, u64 a1, u64 a2, u64 a3,
        uint4v& U0, uint4v& U1, uint4v& U2, uint4v& U3,
        uint4v& U4, uint4v& U5, uint4v& U6, uint4v& U7) {
    if (LOCAL) asm volatile(
        "global_load_dwordx4 %0, %8, off sc0\n\t"
        "global_load_dwordx4 %1, %8, off offset:16 sc0\n\t"
        "global_load_dwordx4 %2, %9, off sc0\n\t"
        "global_load_dwordx4 %3, %9, off offset:16 sc0\n\t"
        "global_load_dwordx4 %4, %10, off sc0\n\t"
        "global_load_dwordx4 %5, %10, off offset:16 sc0\n\t"
        "global_load_dwordx4 %6, %11, off sc0\n\t"
        "global_load_dwordx4 %7, %11, off offset:16 sc0\n\t"
        "s_waitcnt vmcnt(0)"
        : "=&v"(U0), "=&v"(U1), "=&v"(U2), "=&v"(U3),
          "=&v"(U4), "=&v"(U5), "=&v"(U6), "=&v"(U7)
        : "v"(a0), "v"(a1), "v"(a2), "v"(a3) : "memory");
    else asm volatile(
        "global_load_dwordx4 %0, %8, off sc0 sc1\n\t"
        "global_load_dwordx4 %1, %8, off offset:16 sc0 sc1\n\t"
        "global_load_dwordx4 %2, %9, off sc0 sc1\n\t"
        "global_load_dwordx4 %3, %9, off offset:16 sc0 sc1\n\t"
        "global_load_dwordx4 %4, %10, off sc0 sc1\n\t"
        "global_load_dwordx4 %5, %10, off offset:16 sc0 sc1\n\t"
        "global_load_dwordx4 %6, %11, off sc0 sc1\n\t"
        "global_load_dwordx4 %7, %11, off offset:16 sc0 sc1\n\t"
        "s_waitcnt vmcnt(0)"
        : "=&v"(U0), "=&v"(U1), "=&v"(U2), "=&v"(U3),
          "=&v"(U4), "=&v"(U5), "=&v"(U6), "=&v"(U7)
        : "v"(a0), "v"(a1), "v"(a2), "v"(a3) : "memory");
}

// ---------------------------------------------------------------------------
// Prologue: split weights into hi/lo bf16 MFMA A-fragments (layout unchanged).
// ---------------------------------------------------------------------------
__global__ void prep_weights(const float* __restrict__ W_ih,
                             const float* __restrict__ W_hh,
                             const float* __restrict__ b_ih,
                             const float* __restrict__ b_hh,
                             unsigned short* __restrict__ Wt2,
                             float* __restrict__ bias_r) {
    int gid = blockIdx.x * 256 + threadIdx.x;       // 2^20 positions
    if (gid >= (1 << 20)) return;
    int j   = gid & 7;
    int rwi = (gid >> 3) & 15;
    int kgi = (gid >> 7) & 3;
    int ks  = (gid >> 9) & 15;
    int mt  = (gid >> 13) & 3;
    int s   = (gid >> 15) & 15;
    int layer = gid >> 19;
    int k   = ks * 32 + kgi * 8 + j;
    int row = mt * 256 + s * 16 + rwi;              // original gate row
    float w = (k < 256) ? W_ih[((size_t)layer * 1024 + row) * 256 + k]
                        : W_hh[((size_t)layer * 1024 + row) * 256 + (k - 256)];
    short hi = bf16_rne(w);
    float rem = w - bf16_to_f(hi);
    short lo = bf16_rne(rem);
    size_t base = (((size_t)((layer * 16 + s) * 4 + mt) * 16 + ks) * 1024)
                  + (size_t)kgi * 128 + rwi * 8 + j;
    Wt2[base]       = (unsigned short)hi;
    Wt2[base + 512] = (unsigned short)lo;
    if (k == 0) {
        int ridx = s * 64 + mt * 16 + rwi;
        bias_r[layer * 1024 + ridx] = b_ih[layer * 1024 + row] + b_hh[layer * 1024 + row];
    }
}

// ---------------------------------------------------------------------------
// Persistent 2-layer LSTM, MFMA split-bf16, XCD-local sync — EXACT r9
// protocol. r15 delta: h ring depth 4 -> 8 slots; L0's anti-lap predicate
// relaxes from L1 >= r-1 to L1 >= r-5 (6 rounds of slack). Each layer now
// binds only on its own 16-WG barrier; cross-layer edges are slack-absorbed.
// ---------------------------------------------------------------------------
__global__ __launch_bounds__(256, 1)
void lstm_persistent(const float* __restrict__ x,
                     const unsigned short* __restrict__ Wt2,
                     const float* __restrict__ bias_r,
                     char* __restrict__ h1c, char* __restrict__ h2c,
                     int* __restrict__ cnt)
{
    __shared__ __align__(16) f32x4 red[12][64];    // cross-wave partials, 12 KB
    __shared__ int s_mode, s_bg, s_role;

    const int tid   = threadIdx.x;
    const int wave  = tid >> 6;
    const int lane  = tid & 63;

    // ---- registration: discover placement ----
    if (tid == 0) {
        unsigned xcc = (unsigned)__builtin_amdgcn_s_getreg(20 | (3 << 11)) & 7u;
        int* tick = cnt + TICK_OFF;
        int tk = __hip_atomic_fetch_add(tick + xcc, 1, __ATOMIC_RELAXED, __HIP_MEMORY_SCOPE_AGENT);
        __hip_atomic_fetch_add(tick + 8, 1, __ATOMIC_RELEASE, __HIP_MEMORY_SCOPE_AGENT);
        while (__hip_atomic_load(tick + 8, __ATOMIC_ACQUIRE, __HIP_MEMORY_SCOPE_AGENT) < NWG)
            __builtin_amdgcn_s_sleep(8);
        int bal = 1;
        for (int i = 0; i < 8; ++i)
            bal &= (__hip_atomic_load(tick + i, __ATOMIC_RELAXED, __HIP_MEMORY_SCOPE_AGENT) == 32);
        s_mode = bal;
        s_bg   = bal ? (int)xcc : (int)(blockIdx.x & 7);
        s_role = bal ? tk : (int)(((blockIdx.x >> 7) << 4) | ((blockIdx.x & 127) >> 3));
    }
    __syncthreads();

    // ---- purge ALL L2s, then grid barrier (kills stale-dirty-line hazard) ----
    __builtin_amdgcn_fence(__ATOMIC_SEQ_CST, "agent");
    __syncthreads();
    if (tid == 0) {
        int* b2 = cnt + TICK_OFF + 16;
        __hip_atomic_fetch_add(b2, 1, __ATOMIC_RELEASE, __HIP_MEMORY_SCOPE_AGENT);
        while (__hip_atomic_load(b2, __ATOMIC_ACQUIRE, __HIP_MEMORY_SCOPE_AGENT) < NWG)
            __builtin_amdgcn_s_sleep(8);
    }
    __syncthreads();

    const int mode  = s_mode;
    const int bg    = s_bg;
    const int layer = s_role >> 4;
    const int s     = s_role & 15;
    const int b0    = bg * 8;
    const int kg    = lane >> 4;       // k-group within frag
    const int rw    = lane & 15;       // row-within-tile / batch col
    const int rb    = rw & 7;          // duplicated batch for lanes 8..15
    const int batch = b0 + rb;
    int* const fl_base = cnt + bg * 256;         // 32 flags, one 64B line each

    // ---- one-time: A-fragments (weights) into registers ----
    short8v Ahi[4][4], Alo[4][4];      // [mt][k2]
    #pragma unroll
    for (int mt = 0; mt < 4; ++mt)
        #pragma unroll
        for (int k2 = 0; k2 < 4; ++k2) {
            size_t base = (((size_t)((layer * 16 + s) * 4 + mt) * 16 + (wave * 4 + k2)) * 1024)
                          + (size_t)kg * 128 + rw * 8;
            Ahi[mt][k2] = *(const short8v*)((const short*)Wt2 + base);
            Alo[mt][k2] = *(const short8v*)((const short*)Wt2 + base + 512);
        }

    f32x4 biasv[4];
    #pragma unroll
    for (int mt = 0; mt < 4; ++mt)
        biasv[mt] = *(const f32x4*)(bias_r + layer * 1024 + s * 64 + mt * 16 + kg * 4);

    f32x4 creg = {0.f, 0.f, 0.f, 0.f};             // cell state (wave 0, rw<8)

    // ---- initial x prefetch (t=0), layer-0 waves 0/1 only ----
    float4 xr[4][2];
    if (layer == 0 && wave < 2) {
        #pragma unroll
        for (int k2 = 0; k2 < 4; ++k2) {
            const int kbase = (wave * 4 + k2) * 32 + kg * 8;
            const float* xp = x + ((size_t)batch * LT + 0) * LH + kbase;
            xr[k2][0] = *(const float4*)xp;
            xr[k2][1] = *(const float4*)(xp + 4);
        }
    }

    for (int r = 0; r <= LT; ++r) {
        const bool active = (layer == 0) ? (r < LT) : (r >= 1);
        const int t = (layer == 0) ? r : (r - 1);

        // ---- acquire B-fragments ----
        short8v Bhi[4], Blo[4];
        bool useB = false;
        if (active) {
            if (layer == 0 && wave < 2) {
                #pragma unroll
                for (int k2 = 0; k2 < 4; ++k2) {
                    float fv[8] = {xr[k2][0].x, xr[k2][0].y, xr[k2][0].z, xr[k2][0].w,
                                   xr[k2][1].x, xr[k2][1].y, xr[k2][1].z, xr[k2][1].w};
                    short8v bh, bl;
                    #pragma unroll
                    for (int j = 0; j < 8; ++j) {
                        short hb = bf16_rne(fv[j]);
                        bh[j] = hb;
                        bl[j] = bf16_rne(fv[j] - bf16_to_f(hb));
                    }
                    Bhi[k2] = bh; Blo[k2] = bl;
                }
                useB = true;
            } else {
                const char* hbuf; int slot, kofs; bool any;
                if (layer == 0)      { any = (t > 0); hbuf = h1c; slot = (t - 1) & 7; kofs = -256; }
                else if (wave < 2)   { any = true;    hbuf = h1c; slot = t & 7;       kofs = 0;    }
                else                 { any = (t > 0); hbuf = h2c; slot = (t - 1) & 7; kofs = -256; }
                if (any) {
                    const int kb0 = wave * 128 + kg * 8 + kofs;
                    u64 a0, a1, a2, a3;
                    {
                        int kb;
                        kb = kb0;       a0 = (u64)(hbuf + (size_t)((((slot * 64 + batch) * 16) + (kb >> 4)) * 4 + ((kb >> 2) & 3)) * 16);
                        kb = kb0 + 32;  a1 = (u64)(hbuf + (size_t)((((slot * 64 + batch) * 16) + (kb >> 4)) * 4 + ((kb >> 2) & 3)) * 16);
                        kb = kb0 + 64;  a2 = (u64)(hbuf + (size_t)((((slot * 64 + batch) * 16) + (kb >> 4)) * 4 + ((kb >> 2) & 3)) * 16);
                        kb = kb0 + 96;  a3 = (u64)(hbuf + (size_t)((((slot * 64 + batch) * 16) + (kb >> 4)) * 4 + ((kb >> 2) & 3)) * 16);
                    }
                    uint4v U0, U1, U2, U3, U4, U5, U6, U7;
                    if (mode) ld_units<1>(a0, a1, a2, a3, U0, U1, U2, U3, U4, U5, U6, U7);
                    else      ld_units<0>(a0, a1, a2, a3, U0, U1, U2, U3, U4, U5, U6, U7);
                    union { unsigned d[4]; short8v v; } bh, bl;
                    bh.d[0] = U0.x; bh.d[1] = U0.y; bh.d[2] = U1.x; bh.d[3] = U1.y; Bhi[0] = bh.v;
                    bl.d[0] = U0.z; bl.d[1] = U0.w; bl.d[2] = U1.z; bl.d[3] = U1.w; Blo[0] = bl.v;
                    bh.d[0] = U2.x; bh.d[1] = U2.y; bh.d[2] = U3.x; bh.d[3] = U3.y; Bhi[1] = bh.v;
                    bl.d[0] = U2.z; bl.d[1] = U2.w; bl.d[2] = U3.z; bl.d[3] = U3.w; Blo[1] = bl.v;
                    bh.d[0] = U4.x; bh.d[1] = U4.y; bh.d[2] = U5.x; bh.d[3] = U5.y; Bhi[2] = bh.v;
                    bl.d[0] = U4.z; bl.d[1] = U4.w; bl.d[2] = U5.z; bl.d[3] = U5.w; Blo[2] = bl.v;
                    bh.d[0] = U6.x; bh.d[1] = U6.y; bh.d[2] = U7.x; bh.d[3] = U7.y; Bhi[3] = bh.v;
                    bl.d[0] = U6.z; bl.d[1] = U6.w; bl.d[2] = U7.z; bl.d[3] = U7.w; Blo[3] = bl.v;
                    useB = true;
                }
            }
        }

        // ---- MFMA chain ----
        f32x4 acc[4];
        #pragma unroll
        for (int mt = 0; mt < 4; ++mt) acc[mt] = (f32x4){0.f, 0.f, 0.f, 0.f};
        if (useB) {
            #pragma unroll
            for (int k2 = 0; k2 < 4; ++k2)
                #pragma unroll
                for (int mt = 0; mt < 4; ++mt) {
                    acc[mt] = MFMA(Ahi[mt][k2], Bhi[k2], acc[mt]);  // hi*hi
                    acc[mt] = MFMA(Ahi[mt][k2], Blo[k2], acc[mt]);  // hi*lo
                    acc[mt] = MFMA(Alo[mt][k2], Bhi[k2], acc[mt]);  // lo*hi
                }
        }

        // ---- cross-wave k-reduction via LDS ----
        if (active && wave > 0) {
            #pragma unroll
            for (int mt = 0; mt < 4; ++mt) red[(wave - 1) * 4 + mt][lane] = acc[mt];
        }
        __syncthreads();

        if (active && wave == 0) {
            f32x4 gate[4];
            #pragma unroll
            for (int mt = 0; mt < 4; ++mt) {
                f32x4 gs = acc[mt] + biasv[mt];
                #pragma unroll
                for (int w = 0; w < 3; ++w) gs += red[w * 4 + mt][lane];
                gate[mt] = gs;
            }
            float hv[4];
            #pragma unroll
            for (int rr = 0; rr < 4; ++rr) {
                float si = fsigm(gate[0][rr]);
                float sf = fsigm(gate[1][rr]);
                float so = fsigm(gate[3][rr]);
                float gg = ftanh(gate[2][rr]);
                float cn = sf * creg[rr] + si * gg;
                creg[rr] = cn;
                hv[rr] = so * ftanh(cn);
            }
            if (rw < 8) {
                u64 qh = 0, ql = 0;
                #pragma unroll
                for (int rr = 0; rr < 4; ++rr) {
                    unsigned short hb = (unsigned short)bf16_rne(hv[rr]);
                    unsigned short lb = (unsigned short)bf16_rne(hv[rr] - bf16_to_f((short)hb));
                    qh |= ((u64)hb) << (16 * rr);
                    ql |= ((u64)lb) << (16 * rr);
                }
                uint4v dd;
                dd.x = (unsigned)qh; dd.y = (unsigned)(qh >> 32);
                dd.z = (unsigned)ql; dd.w = (unsigned)(ql >> 32);
                char* hbuf = (layer == 0 ? h1c : h2c);
                int unit = (((t & 7) * 64 + (b0 + rw)) * 16 + s) * 4 + kg;
                if (mode) st_unit<1>(hbuf + (size_t)unit * 16, dd);
                else      st_unit<0>(hbuf + (size_t)unit * 16, dd);
            }
        }

        // ---- signal: my round r done (h stores drained first) ----
        if (wave == 0 && r < LT) {
            asm volatile("s_waitcnt vmcnt(0)" ::: "memory");   // h stores at coherence pt
            if (lane == 0) {
                int* fp = fl_base + (layer * 16 + s) * 16;
                if (mode) { st_flag<1>(fp, r + 1); st_flag<0>(fp, r + 1); }
                else      st_flag<0>(fp, r + 1);
            }
        }

        // ---- x prefetch for next round (hides HBM under the poll) ----
        if (layer == 0 && wave < 2 && t + 1 < LT) {
            #pragma unroll
            for (int k2 = 0; k2 < 4; ++k2) {
                const int kbase = (wave * 4 + k2) * 32 + kg * 8;
                const float* xp = x + ((size_t)batch * LT + (t + 1)) * LH + kbase;
                xr[k2][0] = *(const float4*)xp;
                xr[k2][1] = *(const float4*)(xp + 4);
            }
        }

        // ---- wait for round r+1 preconditions (per-layer predicates) ----
        // L0 entering r+1: L0 flags >= r+1, L1 flags >= r-5 (8-slot anti-dep)
        // L1 entering r+1: all 32 flags >= r+1
        if (r < LT) {
            if (wave == 0) {
                const int mL  = lane >> 4;          // member's layer (lanes 0..31)
                const int tgt = (layer == 0) ? ((mL == 0) ? r + 1 : r - 5) : (r + 1);
                int* fp = fl_base + (lane & 31) * 16;
                int it = 0;
                for (;;) {
                    int v = 0x7fffffff;
                    if (lane < 32) {
                        ++it;
                        if (mode && (it & 7) != 0) v = ld_flag<1>(fp);   // local L2
                        else                       v = ld_flag<0>(fp);   // IC escape / mode0
                    }
                    if (__all(v >= tgt)) break;
                    if (!mode) __builtin_amdgcn_s_sleep(1);
                }
            }
            __syncthreads();
        }
    }
}

// ---------------------------------------------------------------------------
// Epilogue: out = h2(2047) @ W_fc^T + b_fc   (slot 2047&7 = 7, 16B units)
// ---------------------------------------------------------------------------
__global__ __launch_bounds__(256)
void fc_kernel(const char* __restrict__ h2c,
               const float* __restrict__ W_fc,
               const float* __restrict__ b_fc,
               float* __restrict__ out) {
    int b = blockIdx.x;
    int o = threadIdx.x;
    __shared__ float hrow[LH];
    for (int k = threadIdx.x; k < LH; k += 256) {
        int unit = ((7 * 64 + b) * 16 + (k >> 4)) * 4 + ((k >> 2) & 3);
        const u64* up = (const u64*)(h2c + (size_t)unit * 16);
        u64 qh = up[0];
        u64 ql = up[1];
        int sh = (k & 3) * 16;
        hrow[k] = bf16_to_f((short)(qh >> sh)) + bf16_to_f((short)(ql >> sh));
    }
    __syncthreads();
    float acc = b_fc[o];
#pragma unroll 8
    for (int k = 0; k < LH; ++k)
        acc = fmaf(W_fc[o * LH + k], hrow[k], acc);
    out[b * LOUT + o] = acc;
}

extern "C" void kernel_launch(void* const* d_in, const int* in_sizes, int n_in,
                              void* d_out, int out_size, void* d_ws, size_t ws_size,
                              hipStream_t stream) {
    const float* x    = (const float*)d_in[0];
    const float* W_ih = (const float*)d_in[1];
    const float* W_hh = (const float*)d_in[2];
    const float* b_ih = (const float*)d_in[3];
    const float* b_hh = (const float*)d_in[4];
    const float* W_fc = (const float*)d_in[5];
    const float* b_fc = (const float*)d_in[6];
    float* out = (float*)d_out;

    char* ws = (char*)d_ws;
    int*            cnt    = (int*)(ws + WS_CNT);
    char*           h1c    = ws + WS_H1;
    char*           h2c    = ws + WS_H2;
    float*          bias_r = (float*)(ws + WS_BIAS);
    unsigned short* Wt2    = (unsigned short*)(ws + WS_WT2);

    hipMemsetAsync(cnt, 0, WS_CNT_SZ, stream);   // fresh flags + tickets each call
    prep_weights<<<(1 << 20) / 256, 256, 0, stream>>>(W_ih, W_hh, b_ih, b_hh, Wt2, bias_r);

    void* args[] = {(void*)&x, (void*)&Wt2, (void*)&bias_r,
                    (void*)&h1c, (void*)&h2c, (void*)&cnt};
    hipError_t e = hipLaunchCooperativeKernel(lstm_persistent, dim3(NWG), dim3(256),
                                              args, 0, stream);
    if (e != hipSuccess) {
        // GPU otherwise idle, 1 WG/CU: 256 WGs co-reside anyway
        lstm_persistent<<<NWG, 256, 0, stream>>>(x, Wt2, bias_r, h1c, h2c, cnt);
    }

    fc_kernel<<<LB, 256, 0, stream>>>(h2c, W_fc, b_fc, out);
}

// Round 16
// 8181.293 us; speedup vs baseline: 2.7107x; 1.0266x over previous
//
#include <hip/hip_runtime.h>
#include <math.h>

typedef unsigned long long u64;
typedef __attribute__((ext_vector_type(8))) short short8v;   // 8 bf16 = 4 VGPR
typedef __attribute__((ext_vector_type(4))) float f32x4;
typedef __attribute__((ext_vector_type(4))) unsigned uint4v;

#define LB 64
#define LT 2048
#define LH 256
#define LOUT 256
#define NWG 256

// ---------- ws layout (bytes) ----------
#define WS_CNT    0
#define WS_CNT_SZ (12 * 1024)
#define TICK_OFF  2048
// h: [slot(8)][batch(64)][s(16)][kg(4)] 16B units -> 512 KB per layer
#define WS_H1     (64 * 1024)
#define WS_H2     (WS_H1 + 512 * 1024)
#define WS_BIAS   (WS_H2 + 512 * 1024)
#define WS_WT2    (2 * 1024 * 1024)
#define MFMA(a, b, c) __builtin_amdgcn_mfma_f32_16x16x32_bf16(a, b, c, 0, 0, 0)

__device__ __host__ __forceinline__ short bf16_rne(float f) {
    unsigned u = __builtin_bit_cast(unsigned, f);
    unsigned r = (u + 0x7fffu + ((u >> 16) & 1u)) >> 16;
    return (short)r;
}
__device__ __forceinline__ float bf16_to_f(short s) {
    unsigned u = ((unsigned)(unsigned short)s) << 16;
    return __builtin_bit_cast(float, u);
}
__device__ __forceinline__ float fsigm(float g) {
    return __builtin_amdgcn_rcpf(1.f + __builtin_amdgcn_exp2f(g * -1.44269504f));
}
__device__ __forceinline__ float ftanh(float g) {
    return __builtin_amdgcn_rcpf(1.f + __builtin_amdgcn_exp2f(g * -2.88539008f)) * 2.f - 1.f;
}

// ---- cache-scope ops: LOCAL=1 -> sc0 (XCD-L2); LOCAL=0 -> sc0 sc1 (IC) ----
// r9-proven: flags dual-published + 1/8 IC-escape polls. r16: the sc1 publish
// is issued by WAVE 1 (after an LDS handshake) so its ~600-900cy IC ack
// drains in parallel with wave0's poll instead of serializing before it.
template <int LOCAL>
__device__ __forceinline__ int ld_flag(const int* p) {
    int v; u64 a = (u64)p;
    if (LOCAL) asm volatile("global_load_dword %0, %1, off sc0\n\ts_waitcnt vmcnt(0)"
                            : "=&v"(v) : "v"(a) : "memory");
    else       asm volatile("global_load_dword %0, %1, off sc0 sc1\n\ts_waitcnt vmcnt(0)"
                            : "=&v"(v) : "v"(a) : "memory");
    return v;
}
template <int LOCAL>
__device__ __forceinline__ void st_flag(int* p, int v) {
    u64 a = (u64)p;
    if (LOCAL) asm volatile("global_store_dword %0, %1, off sc0" :: "v"(a), "v"(v) : "memory");
    else       asm volatile("global_store_dword %0, %1, off sc0 sc1" :: "v"(a), "v"(v) : "memory");
}
template <int LOCAL>
__device__ __forceinline__ void st_unit(void* p, uint4v d) {
    u64 a = (u64)p;
    if (LOCAL) asm volatile("global_store_dwordx4 %0, %1, off sc0" :: "v"(a), "v"(d) : "memory");
    else       asm volatile("global_store_dwordx4 %0, %1, off sc0 sc1" :: "v"(a), "v"(d) : "memory");
}
template <int LOCAL>
__device__ __forceinline__ void ld_units(u64 a0, u64 a1, u64 a2, u64 a3,
        uint4v& U0, uint4v& U1, uint4v& U2, uint4v& U3,
        uint4v& U4, uint4v& U5, uint4v& U6, uint4v& U7) {
    if (LOCAL) asm volatile(
        "global_load_dwordx4 %0, %8, off sc0\n\t"
        "global_load_dwordx4 %1, %8, off offset:16 sc0\n\t"
        "global_load_dwordx4 %2, %9, off sc0\n\t"
        "global_load_dwordx4 %3, %9, off offset:16 sc0\n\t"
        "global_load_dwordx4 %4, %10, off sc0\n\t"
        "global_load_dwordx4 %5, %10, off offset:16 sc0\n\t"
        "global_load_dwordx4 %6, %11, off sc0\n\t"
        "global_load_dwordx4 %7, %11, off offset:16 sc0\n\t"
        "s_waitcnt vmcnt(0)"
        : "=&v"(U0), "=&v"(U1), "=&v"(U2), "=&v"(U3),
          "=&v"(U4), "=&v"(U5), "=&v"(U6), "=&v"(U7)
        : "v"(a0), "v"(a1), "v"(a2), "v"(a3) : "memory");
    else asm volatile(
        "global_load_dwordx4 %0, %8, off sc0 sc1\n\t"
        "global_load_dwordx4 %1, %8, off offset:16 sc0 sc1\n\t"
        "global_load_dwordx4 %2, %9, off sc0 sc1\n\t"
        "global_load_dwordx4 %3, %9, off offset:16 sc0 sc1\n\t"
        "global_load_dwordx4 %4, %10, off sc0 sc1\n\t"
        "global_load_dwordx4 %5, %10, off offset:16 sc0 sc1\n\t"
        "global_load_dwordx4 %6, %11, off sc0 sc1\n\t"
        "global_load_dwordx4 %7, %11, off offset:16 sc0 sc1\n\t"
        "s_waitcnt vmcnt(0)"
        : "=&v"(U0), "=&v"(U1), "=&v"(U2), "=&v"(U3),
          "=&v"(U4), "=&v"(U5), "=&v"(U6), "=&v"(U7)
        : "v"(a0), "v"(a1), "v"(a2), "v"(a3) : "memory");
}

// ---------------------------------------------------------------------------
// Prologue: split weights into hi/lo bf16 MFMA A-fragments (layout unchanged).
// ---------------------------------------------------------------------------
__global__ void prep_weights(const float* __restrict__ W_ih,
                             const float* __restrict__ W_hh,
                             const float* __restrict__ b_ih,
                             const float* __restrict__ b_hh,
                             unsigned short* __restrict__ Wt2,
                             float* __restrict__ bias_r) {
    int gid = blockIdx.x * 256 + threadIdx.x;       // 2^20 positions
    if (gid >= (1 << 20)) return;
    int j   = gid & 7;
    int rwi = (gid >> 3) & 15;
    int kgi = (gid >> 7) & 3;
    int ks  = (gid >> 9) & 15;
    int mt  = (gid >> 13) & 3;
    int s   = (gid >> 15) & 15;
    int layer = gid >> 19;
    int k   = ks * 32 + kgi * 8 + j;
    int row = mt * 256 + s * 16 + rwi;              // original gate row
    float w = (k < 256) ? W_ih[((size_t)layer * 1024 + row) * 256 + k]
                        : W_hh[((size_t)layer * 1024 + row) * 256 + (k - 256)];
    short hi = bf16_rne(w);
    float rem = w - bf16_to_f(hi);
    short lo = bf16_rne(rem);
    size_t base = (((size_t)((layer * 16 + s) * 4 + mt) * 16 + ks) * 1024)
                  + (size_t)kgi * 128 + rwi * 8 + j;
    Wt2[base]       = (unsigned short)hi;
    Wt2[base + 512] = (unsigned short)lo;
    if (k == 0) {
        int ridx = s * 64 + mt * 16 + rwi;
        bias_r[layer * 1024 + ridx] = b_ih[layer * 1024 + row] + b_hh[layer * 1024 + row];
    }
}

// ---------------------------------------------------------------------------
// Persistent 2-layer LSTM, MFMA split-bf16, XCD-local sync — r15 structure
// (8-slot rings, L1>=r-5 anti-dep). r16 delta: sc1 flag publish offloaded to
// wave1 via LDS handshake; wave0 publishes sc0-only (local ~200cy ack).
// ---------------------------------------------------------------------------
__global__ __launch_bounds__(256, 1)
void lstm_persistent(const float* __restrict__ x,
                     const unsigned short* __restrict__ Wt2,
                     const float* __restrict__ bias_r,
                     char* __restrict__ h1c, char* __restrict__ h2c,
                     int* __restrict__ cnt)
{
    __shared__ __align__(16) f32x4 red[12][64];    // cross-wave partials, 12 KB
    __shared__ int s_mode, s_bg, s_role;
    __shared__ int ack_marker;                     // wave0 -> wave1 handshake

    const int tid   = threadIdx.x;
    const int wave  = tid >> 6;
    const int lane  = tid & 63;

    // ---- registration: discover placement ----
    if (tid == 0) {
        ack_marker = 0;
        unsigned xcc = (unsigned)__builtin_amdgcn_s_getreg(20 | (3 << 11)) & 7u;
        int* tick = cnt + TICK_OFF;
        int tk = __hip_atomic_fetch_add(tick + xcc, 1, __ATOMIC_RELAXED, __HIP_MEMORY_SCOPE_AGENT);
        __hip_atomic_fetch_add(tick + 8, 1, __ATOMIC_RELEASE, __HIP_MEMORY_SCOPE_AGENT);
        while (__hip_atomic_load(tick + 8, __ATOMIC_ACQUIRE, __HIP_MEMORY_SCOPE_AGENT) < NWG)
            __builtin_amdgcn_s_sleep(8);
        int bal = 1;
        for (int i = 0; i < 8; ++i)
            bal &= (__hip_atomic_load(tick + i, __ATOMIC_RELAXED, __HIP_MEMORY_SCOPE_AGENT) == 32);
        s_mode = bal;
        s_bg   = bal ? (int)xcc : (int)(blockIdx.x & 7);
        s_role = bal ? tk : (int)(((blockIdx.x >> 7) << 4) | ((blockIdx.x & 127) >> 3));
    }
    __syncthreads();

    // ---- purge ALL L2s, then grid barrier (kills stale-dirty-line hazard) ----
    __builtin_amdgcn_fence(__ATOMIC_SEQ_CST, "agent");
    __syncthreads();
    if (tid == 0) {
        int* b2 = cnt + TICK_OFF + 16;
        __hip_atomic_fetch_add(b2, 1, __ATOMIC_RELEASE, __HIP_MEMORY_SCOPE_AGENT);
        while (__hip_atomic_load(b2, __ATOMIC_ACQUIRE, __HIP_MEMORY_SCOPE_AGENT) < NWG)
            __builtin_amdgcn_s_sleep(8);
    }
    __syncthreads();

    const int mode  = s_mode;
    const int bg    = s_bg;
    const int layer = s_role >> 4;
    const int s     = s_role & 15;
    const int b0    = bg * 8;
    const int kg    = lane >> 4;       // k-group within frag
    const int rw    = lane & 15;       // row-within-tile / batch col
    const int rb    = rw & 7;          // duplicated batch for lanes 8..15
    const int batch = b0 + rb;
    int* const fl_base = cnt + bg * 256;         // 32 flags, one 64B line each
    int* const myfp    = fl_base + (layer * 16 + s) * 16;

    // ---- one-time: A-fragments (weights) into registers ----
    short8v Ahi[4][4], Alo[4][4];      // [mt][k2]
    #pragma unroll
    for (int mt = 0; mt < 4; ++mt)
        #pragma unroll
        for (int k2 = 0; k2 < 4; ++k2) {
            size_t base = (((size_t)((layer * 16 + s) * 4 + mt) * 16 + (wave * 4 + k2)) * 1024)
                          + (size_t)kg * 128 + rw * 8;
            Ahi[mt][k2] = *(const short8v*)((const short*)Wt2 + base);
            Alo[mt][k2] = *(const short8v*)((const short*)Wt2 + base + 512);
        }

    f32x4 biasv[4];
    #pragma unroll
    for (int mt = 0; mt < 4; ++mt)
        biasv[mt] = *(const f32x4*)(bias_r + layer * 1024 + s * 64 + mt * 16 + kg * 4);

    f32x4 creg = {0.f, 0.f, 0.f, 0.f};             // cell state (wave 0, rw<8)

    // ---- initial x prefetch (t=0), layer-0 waves 0/1 only ----
    float4 xr[4][2];
    if (layer == 0 && wave < 2) {
        #pragma unroll
        for (int k2 = 0; k2 < 4; ++k2) {
            const int kbase = (wave * 4 + k2) * 32 + kg * 8;
            const float* xp = x + ((size_t)batch * LT + 0) * LH + kbase;
            xr[k2][0] = *(const float4*)xp;
            xr[k2][1] = *(const float4*)(xp + 4);
        }
    }

    for (int r = 0; r <= LT; ++r) {
        const bool active = (layer == 0) ? (r < LT) : (r >= 1);
        const int t = (layer == 0) ? r : (r - 1);

        // ---- acquire B-fragments ----
        short8v Bhi[4], Blo[4];
        bool useB = false;
        if (active) {
            if (layer == 0 && wave < 2) {
                #pragma unroll
                for (int k2 = 0; k2 < 4; ++k2) {
                    float fv[8] = {xr[k2][0].x, xr[k2][0].y, xr[k2][0].z, xr[k2][0].w,
                                   xr[k2][1].x, xr[k2][1].y, xr[k2][1].z, xr[k2][1].w};
                    short8v bh, bl;
                    #pragma unroll
                    for (int j = 0; j < 8; ++j) {
                        short hb = bf16_rne(fv[j]);
                        bh[j] = hb;
                        bl[j] = bf16_rne(fv[j] - bf16_to_f(hb));
                    }
                    Bhi[k2] = bh; Blo[k2] = bl;
                }
                useB = true;
            } else {
                const char* hbuf; int slot, kofs; bool any;
                if (layer == 0)      { any = (t > 0); hbuf = h1c; slot = (t - 1) & 7; kofs = -256; }
                else if (wave < 2)   { any = true;    hbuf = h1c; slot = t & 7;       kofs = 0;    }
                else                 { any = (t > 0); hbuf = h2c; slot = (t - 1) & 7; kofs = -256; }
                if (any) {
                    const int kb0 = wave * 128 + kg * 8 + kofs;
                    u64 a0, a1, a2, a3;
                    {
                        int kb;
                        kb = kb0;       a0 = (u64)(hbuf + (size_t)((((slot * 64 + batch) * 16) + (kb >> 4)) * 4 + ((kb >> 2) & 3)) * 16);
                        kb = kb0 + 32;  a1 = (u64)(hbuf + (size_t)((((slot * 64 + batch) * 16) + (kb >> 4)) * 4 + ((kb >> 2) & 3)) * 16);
                        kb = kb0 + 64;  a2 = (u64)(hbuf + (size_t)((((slot * 64 + batch) * 16) + (kb >> 4)) * 4 + ((kb >> 2) & 3)) * 16);
                        kb = kb0 + 96;  a3 = (u64)(hbuf + (size_t)((((slot * 64 + batch) * 16) + (kb >> 4)) * 4 + ((kb >> 2) & 3)) * 16);
                    }
                    uint4v U0, U1, U2, U3, U4, U5, U6, U7;
                    if (mode) ld_units<1>(a0, a1, a2, a3, U0, U1, U2, U3, U4, U5, U6, U7);
                    else      ld_units<0>(a0, a1, a2, a3, U0, U1, U2, U3, U4, U5, U6, U7);
                    union { unsigned d[4]; short8v v; } bh, bl;
                    bh.d[0] = U0.x; bh.d[1] = U0.y; bh.d[2] = U1.x; bh.d[3] = U1.y; Bhi[0] = bh.v;
                    bl.d[0] = U0.z; bl.d[1] = U0.w; bl.d[2] = U1.z; bl.d[3] = U1.w; Blo[0] = bl.v;
                    bh.d[0] = U2.x; bh.d[1] = U2.y; bh.d[2] = U3.x; bh.d[3] = U3.y; Bhi[1] = bh.v;
                    bl.d[0] = U2.z; bl.d[1] = U2.w; bl.d[2] = U3.z; bl.d[3] = U3.w; Blo[1] = bl.v;
                    bh.d[0] = U4.x; bh.d[1] = U4.y; bh.d[2] = U5.x; bh.d[3] = U5.y; Bhi[2] = bh.v;
                    bl.d[0] = U4.z; bl.d[1] = U4.w; bl.d[2] = U5.z; bl.d[3] = U5.w; Blo[2] = bl.v;
                    bh.d[0] = U6.x; bh.d[1] = U6.y; bh.d[2] = U7.x; bh.d[3] = U7.y; Bhi[3] = bh.v;
                    bl.d[0] = U6.z; bl.d[1] = U6.w; bl.d[2] = U7.z; bl.d[3] = U7.w; Blo[3] = bl.v;
                    useB = true;
                }
            }
        }

        // ---- MFMA chain ----
        f32x4 acc[4];
        #pragma unroll
        for (int mt = 0; mt < 4; ++mt) acc[mt] = (f32x4){0.f, 0.f, 0.f, 0.f};
        if (useB) {
            #pragma unroll
            for (int k2 = 0; k2 < 4; ++k2)
                #pragma unroll
                for (int mt = 0; mt < 4; ++mt) {
                    acc[mt] = MFMA(Ahi[mt][k2], Bhi[k2], acc[mt]);  // hi*hi
                    acc[mt] = MFMA(Ahi[mt][k2], Blo[k2], acc[mt]);  // hi*lo
                    acc[mt] = MFMA(Alo[mt][k2], Bhi[k2], acc[mt]);  // lo*hi
                }
        }

        // ---- cross-wave k-reduction via LDS ----
        if (active && wave > 0) {
            #pragma unroll
            for (int mt = 0; mt < 4; ++mt) red[(wave - 1) * 4 + mt][lane] = acc[mt];
        }
        __syncthreads();

        if (active && wave == 0) {
            f32x4 gate[4];
            #pragma unroll
            for (int mt = 0; mt < 4; ++mt) {
                f32x4 gs = acc[mt] + biasv[mt];
                #pragma unroll
                for (int w = 0; w < 3; ++w) gs += red[w * 4 + mt][lane];
                gate[mt] = gs;
            }
            float hv[4];
            #pragma unroll
            for (int rr = 0; rr < 4; ++rr) {
                float si = fsigm(gate[0][rr]);
                float sf = fsigm(gate[1][rr]);
                float so = fsigm(gate[3][rr]);
                float gg = ftanh(gate[2][rr]);
                float cn = sf * creg[rr] + si * gg;
                creg[rr] = cn;
                hv[rr] = so * ftanh(cn);
            }
            if (rw < 8) {
                u64 qh = 0, ql = 0;
                #pragma unroll
                for (int rr = 0; rr < 4; ++rr) {
                    unsigned short hb = (unsigned short)bf16_rne(hv[rr]);
                    unsigned short lb = (unsigned short)bf16_rne(hv[rr] - bf16_to_f((short)hb));
                    qh |= ((u64)hb) << (16 * rr);
                    ql |= ((u64)lb) << (16 * rr);
                }
                uint4v dd;
                dd.x = (unsigned)qh; dd.y = (unsigned)(qh >> 32);
                dd.z = (unsigned)ql; dd.w = (unsigned)(ql >> 32);
                char* hbuf = (layer == 0 ? h1c : h2c);
                int unit = (((t & 7) * 64 + (b0 + rw)) * 16 + s) * 4 + kg;
                if (mode) st_unit<1>(hbuf + (size_t)unit * 16, dd);
                else      st_unit<0>(hbuf + (size_t)unit * 16, dd);
            }
        }

        // ---- signal: my round r done (h stores drained first) ----
        if (wave == 0 && r < LT) {
            asm volatile("s_waitcnt vmcnt(0)" ::: "memory");   // h stores at coherence pt
            if (lane == 0) {
                if (mode) {
                    st_flag<1>(myfp, r + 1);     // local publish: ~200cy ack
                    __hip_atomic_store(&ack_marker, r + 1, __ATOMIC_RELEASE,
                                       __HIP_MEMORY_SCOPE_WORKGROUP);
                } else {
                    st_flag<0>(myfp, r + 1);
                }
            }
        }

        // ---- x prefetch for next round (hides HBM under the poll) ----
        if (layer == 0 && wave < 2 && t + 1 < LT) {
            #pragma unroll
            for (int k2 = 0; k2 < 4; ++k2) {
                const int kbase = (wave * 4 + k2) * 32 + kg * 8;
                const float* xp = x + ((size_t)batch * LT + (t + 1)) * LH + kbase;
                xr[k2][0] = *(const float4*)xp;
                xr[k2][1] = *(const float4*)(xp + 4);
            }
        }

        // ---- wave1: offloaded IC publish (mode 1); ack hides under poll ----
        if (mode && wave == 1 && lane == 0 && r < LT) {
            while (__hip_atomic_load(&ack_marker, __ATOMIC_ACQUIRE,
                                     __HIP_MEMORY_SCOPE_WORKGROUP) < r + 1) { }
            st_flag<0>(myfp, r + 1);             // IC publish, drains at barrier
        }

        // ---- wait for round r+1 preconditions (per-layer predicates) ----
        // L0 entering r+1: L0 flags >= r+1, L1 flags >= r-5 (8-slot anti-dep)
        // L1 entering r+1: all 32 flags >= r+1
        if (r < LT) {
            if (wave == 0) {
                const int mL  = lane >> 4;          // member's layer (lanes 0..31)
                const int tgt = (layer == 0) ? ((mL == 0) ? r + 1 : r - 5) : (r + 1);
                int* fp = fl_base + (lane & 31) * 16;
                int it = 0;
                for (;;) {
                    int v = 0x7fffffff;
                    if (lane < 32) {
                        ++it;
                        if (mode && (it & 7) != 0) v = ld_flag<1>(fp);   // local L2
                        else                       v = ld_flag<0>(fp);   // IC escape / mode0
                    }
                    if (__all(v >= tgt)) break;
                    if (!mode) __builtin_amdgcn_s_sleep(1);
                }
            }
            __syncthreads();
        }
    }
}

// ---------------------------------------------------------------------------
// Epilogue: out = h2(2047) @ W_fc^T + b_fc   (slot 2047&7 = 7, 16B units)
// ---------------------------------------------------------------------------
__global__ __launch_bounds__(256)
void fc_kernel(const char* __restrict__ h2c,
               const float* __restrict__ W_fc,
               const float* __restrict__ b_fc,
               float* __restrict__ out) {
    int b = blockIdx.x;
    int o = threadIdx.x;
    __shared__ float hrow[LH];
    for (int k = threadIdx.x; k < LH; k += 256) {
        int unit = ((7 * 64 + b) * 16 + (k >> 4)) * 4 + ((k >> 2) & 3);
        const u64* up = (const u64*)(h2c + (size_t)unit * 16);
        u64 qh = up[0];
        u64 ql = up[1];
        int sh = (k & 3) * 16;
        hrow[k] = bf16_to_f((short)(qh >> sh)) + bf16_to_f((short)(ql >> sh));
    }
    __syncthreads();
    float acc = b_fc[o];
#pragma unroll 8
    for (int k = 0; k < LH; ++k)
        acc = fmaf(W_fc[o * LH + k], hrow[k], acc);
    out[b * LOUT + o] = acc;
}

extern "C" void kernel_launch(void* const* d_in, const int* in_sizes, int n_in,
                              void* d_out, int out_size, void* d_ws, size_t ws_size,
                              hipStream_t stream) {
    const float* x    = (const float*)d_in[0];
    const float* W_ih = (const float*)d_in[1];
    const float* W_hh = (const float*)d_in[2];
    const float* b_ih = (const float*)d_in[3];
    const float* b_hh = (const float*)d_in[4];
    const float* W_fc = (const float*)d_in[5];
    const float* b_fc = (const float*)d_in[6];
    float* out = (float*)d_out;

    char* ws = (char*)d_ws;
    int*            cnt    = (int*)(ws + WS_CNT);
    char*           h1c    = ws + WS_H1;
    char*           h2c    = ws + WS_H2;
    float*          bias_r = (float*)(ws + WS_BIAS);
    unsigned short* Wt2    = (unsigned short*)(ws + WS_WT2);

    hipMemsetAsync(cnt, 0, WS_CNT_SZ, stream);   // fresh flags + tickets each call
    prep_weights<<<(1 << 20) / 256, 256, 0, stream>>>(W_ih, W_hh, b_ih, b_hh, Wt2, bias_r);

    void* args[] = {(void*)&x, (void*)&Wt2, (void*)&bias_r,
                    (void*)&h1c, (void*)&h2c, (void*)&cnt};
    hipError_t e = hipLaunchCooperativeKernel(lstm_persistent, dim3(NWG), dim3(256),
                                              args, 0, stream);
    if (e != hipSuccess) {
        // GPU otherwise idle, 1 WG/CU: 256 WGs co-reside anyway
        lstm_persistent<<<NWG, 256, 0, stream>>>(x, Wt2, bias_r, h1c, h2c, cnt);
    }

    fc_kernel<<<LB, 256, 0, stream>>>(h2c, W_fc, b_fc, out);
}

// Round 18
// 8173.158 us; speedup vs baseline: 2.7134x; 1.0010x over previous
//
#include <hip/hip_runtime.h>
#include <math.h>

typedef unsigned long long u64;
typedef __attribute__((ext_vector_type(8))) short short8v;   // 8 bf16 = 4 VGPR
typedef __attribute__((ext_vector_type(4))) float f32x4;
typedef __attribute__((ext_vector_type(4))) unsigned uint4v;

#define LB 64
#define LT 2048
#define LH 256
#define LOUT 256
#define NWG 256

// ---------- ws layout (bytes) ----------
#define WS_CNT    0
#define WS_CNT_SZ (12 * 1024)
#define TICK_OFF  2048
// h: [slot(8)][batch(64)][s(16)][kg(4)] 16B units -> 512 KB per layer
#define WS_H1     (64 * 1024)
#define WS_H2     (WS_H1 + 512 * 1024)
#define WS_BIAS   (WS_H2 + 512 * 1024)
#define WS_WT2    (2 * 1024 * 1024)
#define MFMA(a, b, c) __builtin_amdgcn_mfma_f32_16x16x32_bf16(a, b, c, 0, 0, 0)

__device__ __host__ __forceinline__ short bf16_rne(float f) {
    unsigned u = __builtin_bit_cast(unsigned, f);
    unsigned r = (u + 0x7fffu + ((u >> 16) & 1u)) >> 16;
    return (short)r;
}
__device__ __forceinline__ float bf16_to_f(short s) {
    unsigned u = ((unsigned)(unsigned short)s) << 16;
    return __builtin_bit_cast(float, u);
}
__device__ __forceinline__ float fsigm(float g) {
    return __builtin_amdgcn_rcpf(1.f + __builtin_amdgcn_exp2f(g * -1.44269504f));
}
__device__ __forceinline__ float ftanh(float g) {
    return __builtin_amdgcn_rcpf(1.f + __builtin_amdgcn_exp2f(g * -2.88539008f)) * 2.f - 1.f;
}

// ---- cache-scope ops: LOCAL=1 -> sc0 (XCD-L2); LOCAL=0 -> sc0 sc1 (IC) ----
// r9-proven: flags dual-published + 1/8 IC-escape polls (r17's 1/64 variant
// failed the determinism tripwire; 1/8 is the verified setting).
template <int LOCAL>
__device__ __forceinline__ int ld_flag(const int* p) {
    int v; u64 a = (u64)p;
    if (LOCAL) asm volatile("global_load_dword %0, %1, off sc0\n\ts_waitcnt vmcnt(0)"
                            : "=&v"(v) : "v"(a) : "memory");
    else       asm volatile("global_load_dword %0, %1, off sc0 sc1\n\ts_waitcnt vmcnt(0)"
                            : "=&v"(v) : "v"(a) : "memory");
    return v;
}
template <int LOCAL>
__device__ __forceinline__ void st_flag(int* p, int v) {
    u64 a = (u64)p;
    if (LOCAL) asm volatile("global_store_dword %0, %1, off sc0" :: "v"(a), "v"(v) : "memory");
    else       asm volatile("global_store_dword %0, %1, off sc0 sc1" :: "v"(a), "v"(v) : "memory");
}
template <int LOCAL>
__device__ __forceinline__ void st_unit(void* p, uint4v d) {
    u64 a = (u64)p;
    if (LOCAL) asm volatile("global_store_dwordx4 %0, %1, off sc0" :: "v"(a), "v"(d) : "memory");
    else       asm volatile("global_store_dwordx4 %0, %1, off sc0 sc1" :: "v"(a), "v"(d) : "memory");
}
template <int LOCAL>
__device__ __forceinline__ void ld_units(u64 a0, u64 a1, u64 a2, u64 a3,
        uint4v& U0, uint4v& U1, uint4v& U2, uint4v& U3,
        uint4v& U4, uint4v& U5, uint4v& U6, uint4v& U7) {
    if (LOCAL) asm volatile(
        "global_load_dwordx4 %0, %8, off sc0\n\t"
        "global_load_dwordx4 %1, %8, off offset:16 sc0\n\t"
        "global_load_dwordx4 %2, %9, off sc0\n\t"
        "global_load_dwordx4 %3, %9, off offset:16 sc0\n\t"
        "global_load_dwordx4 %4, %10, off sc0\n\t"
        "global_load_dwordx4 %5, %10, off offset:16 sc0\n\t"
        "global_load_dwordx4 %6, %11, off sc0\n\t"
        "global_load_dwordx4 %7, %11, off offset:16 sc0\n\t"
        "s_waitcnt vmcnt(0)"
        : "=&v"(U0), "=&v"(U1), "=&v"(U2), "=&v"(U3),
          "=&v"(U4), "=&v"(U5), "=&v"(U6), "=&v"(U7)
        : "v"(a0), "v"(a1), "v"(a2), "v"(a3) : "memory");
    else asm volatile(
        "global_load_dwordx4 %0, %8, off sc0 sc1\n\t"
        "global_load_dwordx4 %1, %8, off offset:16 sc0 sc1\n\t"
        "global_load_dwordx4 %2, %9, off sc0 sc1\n\t"
        "global_load_dwordx4 %3, %9, off offset:16 sc0 sc1\n\t"
        "global_load_dwordx4 %4, %10, off sc0 sc1\n\t"
        "global_load_dwordx4 %5, %10, off offset:16 sc0 sc1\n\t"
        "global_load_dwordx4 %6, %11, off sc0 sc1\n\t"
        "global_load_dwordx4 %7, %11, off offset:16 sc0 sc1\n\t"
        "s_waitcnt vmcnt(0)"
        : "=&v"(U0), "=&v"(U1), "=&v"(U2), "=&v"(U3),
          "=&v"(U4), "=&v"(U5), "=&v"(U6), "=&v"(U7)
        : "v"(a0), "v"(a1), "v"(a2), "v"(a3) : "memory");
}

// ---------------------------------------------------------------------------
// Prologue: split weights into hi/lo bf16 MFMA A-fragments (layout unchanged).
// ---------------------------------------------------------------------------
__global__ void prep_weights(const float* __restrict__ W_ih,
                             const float* __restrict__ W_hh,
                             const float* __restrict__ b_ih,
                             const float* __restrict__ b_hh,
                             unsigned short* __restrict__ Wt2,
                             float* __restrict__ bias_r) {
    int gid = blockIdx.x * 256 + threadIdx.x;       // 2^20 positions
    if (gid >= (1 << 20)) return;
    int j   = gid & 7;
    int rwi = (gid >> 3) & 15;
    int kgi = (gid >> 7) & 3;
    int ks  = (gid >> 9) & 15;
    int mt  = (gid >> 13) & 3;
    int s   = (gid >> 15) & 15;
    int layer = gid >> 19;
    int k   = ks * 32 + kgi * 8 + j;
    int row = mt * 256 + s * 16 + rwi;              // original gate row
    float w = (k < 256) ? W_ih[((size_t)layer * 1024 + row) * 256 + k]
                        : W_hh[((size_t)layer * 1024 + row) * 256 + (k - 256)];
    short hi = bf16_rne(w);
    float rem = w - bf16_to_f(hi);
    short lo = bf16_rne(rem);
    size_t base = (((size_t)((layer * 16 + s) * 4 + mt) * 16 + ks) * 1024)
                  + (size_t)kgi * 128 + rwi * 8 + j;
    Wt2[base]       = (unsigned short)hi;
    Wt2[base + 512] = (unsigned short)lo;
    if (k == 0) {
        int ridx = s * 64 + mt * 16 + rwi;
        bias_r[layer * 1024 + ridx] = b_ih[layer * 1024 + row] + b_hh[layer * 1024 + row];
    }
}

// ---------------------------------------------------------------------------
// Persistent 2-layer LSTM, MFMA split-bf16, XCD-local sync — r16 final:
// r9 protocol (dual-publish flags, 1/8 IC-escape polls, purge + grid
// barrier) + 8-slot h rings (L1>=r-5 anti-dep) + wave1 sc1-publish offload.
// Verified deterministic at 8.18 ms (r16 bench).
// ---------------------------------------------------------------------------
__global__ __launch_bounds__(256, 1)
void lstm_persistent(const float* __restrict__ x,
                     const unsigned short* __restrict__ Wt2,
                     const float* __restrict__ bias_r,
                     char* __restrict__ h1c, char* __restrict__ h2c,
                     int* __restrict__ cnt)
{
    __shared__ __align__(16) f32x4 red[12][64];    // cross-wave partials, 12 KB
    __shared__ int s_mode, s_bg, s_role;
    __shared__ int ack_marker;                     // wave0 -> wave1 handshake

    const int tid   = threadIdx.x;
    const int wave  = tid >> 6;
    const int lane  = tid & 63;

    // ---- registration: discover placement ----
    if (tid == 0) {
        ack_marker = 0;
        unsigned xcc = (unsigned)__builtin_amdgcn_s_getreg(20 | (3 << 11)) & 7u;
        int* tick = cnt + TICK_OFF;
        int tk = __hip_atomic_fetch_add(tick + xcc, 1, __ATOMIC_RELAXED, __HIP_MEMORY_SCOPE_AGENT);
        __hip_atomic_fetch_add(tick + 8, 1, __ATOMIC_RELEASE, __HIP_MEMORY_SCOPE_AGENT);
        while (__hip_atomic_load(tick + 8, __ATOMIC_ACQUIRE, __HIP_MEMORY_SCOPE_AGENT) < NWG)
            __builtin_amdgcn_s_sleep(8);
        int bal = 1;
        for (int i = 0; i < 8; ++i)
            bal &= (__hip_atomic_load(tick + i, __ATOMIC_RELAXED, __HIP_MEMORY_SCOPE_AGENT) == 32);
        s_mode = bal;
        s_bg   = bal ? (int)xcc : (int)(blockIdx.x & 7);
        s_role = bal ? tk : (int)(((blockIdx.x >> 7) << 4) | ((blockIdx.x & 127) >> 3));
    }
    __syncthreads();

    // ---- purge ALL L2s, then grid barrier (kills stale-dirty-line hazard) ----
    __builtin_amdgcn_fence(__ATOMIC_SEQ_CST, "agent");
    __syncthreads();
    if (tid == 0) {
        int* b2 = cnt + TICK_OFF + 16;
        __hip_atomic_fetch_add(b2, 1, __ATOMIC_RELEASE, __HIP_MEMORY_SCOPE_AGENT);
        while (__hip_atomic_load(b2, __ATOMIC_ACQUIRE, __HIP_MEMORY_SCOPE_AGENT) < NWG)
            __builtin_amdgcn_s_sleep(8);
    }
    __syncthreads();

    const int mode  = s_mode;
    const int bg    = s_bg;
    const int layer = s_role >> 4;
    const int s     = s_role & 15;
    const int b0    = bg * 8;
    const int kg    = lane >> 4;       // k-group within frag
    const int rw    = lane & 15;       // row-within-tile / batch col
    const int rb    = rw & 7;          // duplicated batch for lanes 8..15
    const int batch = b0 + rb;
    int* const fl_base = cnt + bg * 256;         // 32 flags, one 64B line each
    int* const myfp    = fl_base + (layer * 16 + s) * 16;

    // ---- one-time: A-fragments (weights) into registers ----
    short8v Ahi[4][4], Alo[4][4];      // [mt][k2]
    #pragma unroll
    for (int mt = 0; mt < 4; ++mt)
        #pragma unroll
        for (int k2 = 0; k2 < 4; ++k2) {
            size_t base = (((size_t)((layer * 16 + s) * 4 + mt) * 16 + (wave * 4 + k2)) * 1024)
                          + (size_t)kg * 128 + rw * 8;
            Ahi[mt][k2] = *(const short8v*)((const short*)Wt2 + base);
            Alo[mt][k2] = *(const short8v*)((const short*)Wt2 + base + 512);
        }

    f32x4 biasv[4];
    #pragma unroll
    for (int mt = 0; mt < 4; ++mt)
        biasv[mt] = *(const f32x4*)(bias_r + layer * 1024 + s * 64 + mt * 16 + kg * 4);

    f32x4 creg = {0.f, 0.f, 0.f, 0.f};             // cell state (wave 0, rw<8)

    // ---- initial x prefetch (t=0), layer-0 waves 0/1 only ----
    float4 xr[4][2];
    if (layer == 0 && wave < 2) {
        #pragma unroll
        for (int k2 = 0; k2 < 4; ++k2) {
            const int kbase = (wave * 4 + k2) * 32 + kg * 8;
            const float* xp = x + ((size_t)batch * LT + 0) * LH + kbase;
            xr[k2][0] = *(const float4*)xp;
            xr[k2][1] = *(const float4*)(xp + 4);
        }
    }

    for (int r = 0; r <= LT; ++r) {
        const bool active = (layer == 0) ? (r < LT) : (r >= 1);
        const int t = (layer == 0) ? r : (r - 1);

        // ---- acquire B-fragments ----
        short8v Bhi[4], Blo[4];
        bool useB = false;
        if (active) {
            if (layer == 0 && wave < 2) {
                #pragma unroll
                for (int k2 = 0; k2 < 4; ++k2) {
                    float fv[8] = {xr[k2][0].x, xr[k2][0].y, xr[k2][0].z, xr[k2][0].w,
                                   xr[k2][1].x, xr[k2][1].y, xr[k2][1].z, xr[k2][1].w};
                    short8v bh, bl;
                    #pragma unroll
                    for (int j = 0; j < 8; ++j) {
                        short hb = bf16_rne(fv[j]);
                        bh[j] = hb;
                        bl[j] = bf16_rne(fv[j] - bf16_to_f(hb));
                    }
                    Bhi[k2] = bh; Blo[k2] = bl;
                }
                useB = true;
            } else {
                const char* hbuf; int slot, kofs; bool any;
                if (layer == 0)      { any = (t > 0); hbuf = h1c; slot = (t - 1) & 7; kofs = -256; }
                else if (wave < 2)   { any = true;    hbuf = h1c; slot = t & 7;       kofs = 0;    }
                else                 { any = (t > 0); hbuf = h2c; slot = (t - 1) & 7; kofs = -256; }
                if (any) {
                    const int kb0 = wave * 128 + kg * 8 + kofs;
                    u64 a0, a1, a2, a3;
                    {
                        int kb;
                        kb = kb0;       a0 = (u64)(hbuf + (size_t)((((slot * 64 + batch) * 16) + (kb >> 4)) * 4 + ((kb >> 2) & 3)) * 16);
                        kb = kb0 + 32;  a1 = (u64)(hbuf + (size_t)((((slot * 64 + batch) * 16) + (kb >> 4)) * 4 + ((kb >> 2) & 3)) * 16);
                        kb = kb0 + 64;  a2 = (u64)(hbuf + (size_t)((((slot * 64 + batch) * 16) + (kb >> 4)) * 4 + ((kb >> 2) & 3)) * 16);
                        kb = kb0 + 96;  a3 = (u64)(hbuf + (size_t)((((slot * 64 + batch) * 16) + (kb >> 4)) * 4 + ((kb >> 2) & 3)) * 16);
                    }
                    uint4v U0, U1, U2, U3, U4, U5, U6, U7;
                    if (mode) ld_units<1>(a0, a1, a2, a3, U0, U1, U2, U3, U4, U5, U6, U7);
                    else      ld_units<0>(a0, a1, a2, a3, U0, U1, U2, U3, U4, U5, U6, U7);
                    union { unsigned d[4]; short8v v; } bh, bl;
                    bh.d[0] = U0.x; bh.d[1] = U0.y; bh.d[2] = U1.x; bh.d[3] = U1.y; Bhi[0] = bh.v;
                    bl.d[0] = U0.z; bl.d[1] = U0.w; bl.d[2] = U1.z; bl.d[3] = U1.w; Blo[0] = bl.v;
                    bh.d[0] = U2.x; bh.d[1] = U2.y; bh.d[2] = U3.x; bh.d[3] = U3.y; Bhi[1] = bh.v;
                    bl.d[0] = U2.z; bl.d[1] = U2.w; bl.d[2] = U3.z; bl.d[3] = U3.w; Blo[1] = bl.v;
                    bh.d[0] = U4.x; bh.d[1] = U4.y; bh.d[2] = U5.x; bh.d[3] = U5.y; Bhi[2] = bh.v;
                    bl.d[0] = U4.z; bl.d[1] = U4.w; bl.d[2] = U5.z; bl.d[3] = U5.w; Blo[2] = bl.v;
                    bh.d[0] = U6.x; bh.d[1] = U6.y; bh.d[2] = U7.x; bh.d[3] = U7.y; Bhi[3] = bh.v;
                    bl.d[0] = U6.z; bl.d[1] = U6.w; bl.d[2] = U7.z; bl.d[3] = U7.w; Blo[3] = bl.v;
                    useB = true;
                }
            }
        }

        // ---- MFMA chain ----
        f32x4 acc[4];
        #pragma unroll
        for (int mt = 0; mt < 4; ++mt) acc[mt] = (f32x4){0.f, 0.f, 0.f, 0.f};
        if (useB) {
            #pragma unroll
            for (int k2 = 0; k2 < 4; ++k2)
                #pragma unroll
                for (int mt = 0; mt < 4; ++mt) {
                    acc[mt] = MFMA(Ahi[mt][k2], Bhi[k2], acc[mt]);  // hi*hi
                    acc[mt] = MFMA(Ahi[mt][k2], Blo[k2], acc[mt]);  // hi*lo
                    acc[mt] = MFMA(Alo[mt][k2], Bhi[k2], acc[mt]);  // lo*hi
                }
        }

        // ---- cross-wave k-reduction via LDS ----
        if (active && wave > 0) {
            #pragma unroll
            for (int mt = 0; mt < 4; ++mt) red[(wave - 1) * 4 + mt][lane] = acc[mt];
        }
        __syncthreads();

        if (active && wave == 0) {
            f32x4 gate[4];
            #pragma unroll
            for (int mt = 0; mt < 4; ++mt) {
                f32x4 gs = acc[mt] + biasv[mt];
                #pragma unroll
                for (int w = 0; w < 3; ++w) gs += red[w * 4 + mt][lane];
                gate[mt] = gs;
            }
            float hv[4];
            #pragma unroll
            for (int rr = 0; rr < 4; ++rr) {
                float si = fsigm(gate[0][rr]);
                float sf = fsigm(gate[1][rr]);
                float so = fsigm(gate[3][rr]);
                float gg = ftanh(gate[2][rr]);
                float cn = sf * creg[rr] + si * gg;
                creg[rr] = cn;
                hv[rr] = so * ftanh(cn);
            }
            if (rw < 8) {
                u64 qh = 0, ql = 0;
                #pragma unroll
                for (int rr = 0; rr < 4; ++rr) {
                    unsigned short hb = (unsigned short)bf16_rne(hv[rr]);
                    unsigned short lb = (unsigned short)bf16_rne(hv[rr] - bf16_to_f((short)hb));
                    qh |= ((u64)hb) << (16 * rr);
                    ql |= ((u64)lb) << (16 * rr);
                }
                uint4v dd;
                dd.x = (unsigned)qh; dd.y = (unsigned)(qh >> 32);
                dd.z = (unsigned)ql; dd.w = (unsigned)(ql >> 32);
                char* hbuf = (layer == 0 ? h1c : h2c);
                int unit = (((t & 7) * 64 + (b0 + rw)) * 16 + s) * 4 + kg;
                if (mode) st_unit<1>(hbuf + (size_t)unit * 16, dd);
                else      st_unit<0>(hbuf + (size_t)unit * 16, dd);
            }
        }

        // ---- signal: my round r done (h stores drained first) ----
        if (wave == 0 && r < LT) {
            asm volatile("s_waitcnt vmcnt(0)" ::: "memory");   // h stores at coherence pt
            if (lane == 0) {
                if (mode) {
                    st_flag<1>(myfp, r + 1);     // local publish: ~200cy ack
                    __hip_atomic_store(&ack_marker, r + 1, __ATOMIC_RELEASE,
                                       __HIP_MEMORY_SCOPE_WORKGROUP);
                } else {
                    st_flag<0>(myfp, r + 1);
                }
            }
        }

        // ---- x prefetch for next round (hides HBM under the poll) ----
        if (layer == 0 && wave < 2 && t + 1 < LT) {
            #pragma unroll
            for (int k2 = 0; k2 < 4; ++k2) {
                const int kbase = (wave * 4 + k2) * 32 + kg * 8;
                const float* xp = x + ((size_t)batch * LT + (t + 1)) * LH + kbase;
                xr[k2][0] = *(const float4*)xp;
                xr[k2][1] = *(const float4*)(xp + 4);
            }
        }

        // ---- wave1: offloaded IC publish (mode 1); ack hides under poll ----
        if (mode && wave == 1 && lane == 0 && r < LT) {
            while (__hip_atomic_load(&ack_marker, __ATOMIC_ACQUIRE,
                                     __HIP_MEMORY_SCOPE_WORKGROUP) < r + 1) { }
            st_flag<0>(myfp, r + 1);             // IC publish, drains at barrier
        }

        // ---- wait for round r+1 preconditions (per-layer predicates) ----
        // L0 entering r+1: L0 flags >= r+1, L1 flags >= r-5 (8-slot anti-dep)
        // L1 entering r+1: all 32 flags >= r+1
        if (r < LT) {
            if (wave == 0) {
                const int mL  = lane >> 4;          // member's layer (lanes 0..31)
                const int tgt = (layer == 0) ? ((mL == 0) ? r + 1 : r - 5) : (r + 1);
                int* fp = fl_base + (lane & 31) * 16;
                int it = 0;
                for (;;) {
                    int v = 0x7fffffff;
                    if (lane < 32) {
                        ++it;
                        if (mode && (it & 7) != 0) v = ld_flag<1>(fp);   // local L2
                        else                       v = ld_flag<0>(fp);   // IC escape / mode0
                    }
                    if (__all(v >= tgt)) break;
                    if (!mode) __builtin_amdgcn_s_sleep(1);
                }
            }
            __syncthreads();
        }
    }
}

// ---------------------------------------------------------------------------
// Epilogue: out = h2(2047) @ W_fc^T + b_fc   (slot 2047&7 = 7, 16B units)
// ---------------------------------------------------------------------------
__global__ __launch_bounds__(256)
void fc_kernel(const char* __restrict__ h2c,
               const float* __restrict__ W_fc,
               const float* __restrict__ b_fc,
               float* __restrict__ out) {
    int b = blockIdx.x;
    int o = threadIdx.x;
    __shared__ float hrow[LH];
    for (int k = threadIdx.x; k < LH; k += 256) {
        int unit = ((7 * 64 + b) * 16 + (k >> 4)) * 4 + ((k >> 2) & 3);
        const u64* up = (const u64*)(h2c + (size_t)unit * 16);
        u64 qh = up[0];
        u64 ql = up[1];
        int sh = (k & 3) * 16;
        hrow[k] = bf16_to_f((short)(qh >> sh)) + bf16_to_f((short)(ql >> sh));
    }
    __syncthreads();
    float acc = b_fc[o];
#pragma unroll 8
    for (int k = 0; k < LH; ++k)
        acc = fmaf(W_fc[o * LH + k], hrow[k], acc);
    out[b * LOUT + o] = acc;
}

extern "C" void kernel_launch(void* const* d_in, const int* in_sizes, int n_in,
                              void* d_out, int out_size, void* d_ws, size_t ws_size,
                              hipStream_t stream) {
    const float* x    = (const float*)d_in[0];
    const float* W_ih = (const float*)d_in[1];
    const float* W_hh = (const float*)d_in[2];
    const float* b_ih = (const float*)d_in[3];
    const float* b_hh = (const float*)d_in[4];
    const float* W_fc = (const float*)d_in[5];
    const float* b_fc = (const float*)d_in[6];
    float* out = (float*)d_out;

    char* ws = (char*)d_ws;
    int*            cnt    = (int*)(ws + WS_CNT);
    char*           h1c    = ws + WS_H1;
    char*           h2c    = ws + WS_H2;
    float*          bias_r = (float*)(ws + WS_BIAS);
    unsigned short* Wt2    = (unsigned short*)(ws + WS_WT2);

    hipMemsetAsync(cnt, 0, WS_CNT_SZ, stream);   // fresh flags + tickets each call
    prep_weights<<<(1 << 20) / 256, 256, 0, stream>>>(W_ih, W_hh, b_ih, b_hh, Wt2, bias_r);

    void* args[] = {(void*)&x, (void*)&Wt2, (void*)&bias_r,
                    (void*)&h1c, (void*)&h2c, (void*)&cnt};
    hipError_t e = hipLaunchCooperativeKernel(lstm_persistent, dim3(NWG), dim3(256),
                                              args, 0, stream);
    if (e != hipSuccess) {
        // GPU otherwise idle, 1 WG/CU: 256 WGs co-reside anyway
        lstm_persistent<<<NWG, 256, 0, stream>>>(x, Wt2, bias_r, h1c, h2c, cnt);
    }

    fc_kernel<<<LB, 256, 0, stream>>>(h2c, W_fc, b_fc, out);
}